// Round 8
// baseline (437.748 us; speedup 1.0000x reference)
//
#include <hip/hip_runtime.h>

// GNN with hierarchical virtual nodes. FP32 in/out, int32 indices.
//
//  CSR build: bucketed (dst>>9) two-level sort -> per-bucket-owned colarr.
//  Node list grouped by hb (counting sort) for the VN segment-sum.
//  h rows are 144B: [ssrc fp32 | pad | 64 bf16] -- the phase-A score gather
//  warms the first line of the row phase B gathers (fold ssrc traffic into h).
//  Aggregate softmax referenced to self-loop alpha (shift-invariant).
//  (VN update after the last layer never reaches the output -> skipped)

typedef __attribute__((ext_vector_type(8))) short short8;
typedef __attribute__((ext_vector_type(4))) float f32x4;

__device__ __forceinline__ unsigned short f2bf(float x){      // RNE float->bf16
    unsigned u = __float_as_uint(x);
    unsigned r = (u + 0x7fffu + ((u >> 16) & 1u)) >> 16;
    return (unsigned short)r;
}
__device__ __forceinline__ float bf2f(unsigned short b){
    return __uint_as_float(((unsigned)b) << 16);
}

#define BSHIFT 9
#define CHUNK 4096
#define NSLICE 8
#define HROW 72   // shorts per h row: [0,1]=ssrc fp32, [2..7] pad, [8..71] bf16 x64

// inclusive scan of v across the 256 threads of the block (4 waves)
__device__ __forceinline__ int incl_scan256(int v, int* sums4){
    int lane = threadIdx.x & 63, w = threadIdx.x >> 6;
    int x = v;
    #pragma unroll
    for (int o = 1; o < 64; o <<= 1){ int t = __shfl_up(x, o, 64); if (lane >= o) x += t; }
    __syncthreads();
    if (lane == 63) sums4[w] = x;
    __syncthreads();
    for (int j = 0; j < w; ++j) x += sums4[j];
    return x;
}

// ---------------- bucketed CSR build ----------------
__global__ __launch_bounds__(256) void k_bucket_count(const int* __restrict__ dst, int E, int NB,
                                                      int* __restrict__ bucketCount){
    __shared__ int cnt[256];
    cnt[threadIdx.x] = 0;
    __syncthreads();
    int base = blockIdx.x*CHUNK;
    int lim = min(base + CHUNK, E);
    for (int i = base + threadIdx.x; i < lim; i += 256)
        atomicAdd(&cnt[dst[i] >> BSHIFT], 1);
    __syncthreads();
    if (threadIdx.x < NB && cnt[threadIdx.x])
        atomicAdd(&bucketCount[threadIdx.x], cnt[threadIdx.x]);
}

__global__ __launch_bounds__(256) void k_hb_count(const int* __restrict__ hb, int N,
                                                  int* __restrict__ hbBins){
    __shared__ int cnt[256];
    cnt[threadIdx.x] = 0;
    __syncthreads();
    int base = blockIdx.x*CHUNK;
    int lim = min(base + CHUNK, N);
    for (int i = base + threadIdx.x; i < lim; i += 256)
        atomicAdd(&cnt[hb[i]], 1);
    __syncthreads();
    if (cnt[threadIdx.x])
        atomicAdd(&hbBins[threadIdx.x], cnt[threadIdx.x]);
}

__global__ __launch_bounds__(256) void k_scan_all(const int* __restrict__ bucketCount,
                                                  int NB, int E, int N,
                                                  int* __restrict__ bucketOff,
                                                  int* __restrict__ bucketCur,
                                                  int* __restrict__ rowptr,
                                                  const int* __restrict__ hbBins,
                                                  int* __restrict__ binptr,
                                                  int* __restrict__ bincur){
    __shared__ int sums4[4];
    int tid = threadIdx.x;
    int v = (tid < NB) ? bucketCount[tid] : 0;
    int x = incl_scan256(v, sums4);
    if (tid < NB){ bucketOff[tid] = x - v; bucketCur[tid] = x - v; }
    if (tid == NB-1) bucketOff[NB] = x;
    if (tid == 0) rowptr[N] = E;
    int v2 = hbBins[tid];
    int x2 = incl_scan256(v2, sums4);
    binptr[tid] = x2 - v2;
    bincur[tid] = x2 - v2;
    if (tid == 255) binptr[256] = x2;
}

__global__ __launch_bounds__(256) void k_bucket_place(const int* __restrict__ src,
                                                      const int* __restrict__ dst, int E, int NB,
                                                      int* __restrict__ bucketCur,
                                                      int2* __restrict__ pairs){
    __shared__ int cnt[256], binStart[256], binCur[256], chunkBase[256];
    __shared__ int sums4[4];
    __shared__ int2 lp[CHUNK];
    int tid = threadIdx.x;
    cnt[tid] = 0; binCur[tid] = 0;
    __syncthreads();
    int base = blockIdx.x*CHUNK;
    int s[16], d[16];
    #pragma unroll
    for (int k = 0; k < 16; ++k){
        int i = base + k*256 + tid;
        if (i < E){ s[k] = src[i]; d[k] = dst[i]; atomicAdd(&cnt[d[k] >> BSHIFT], 1); }
        else d[k] = -1;
    }
    __syncthreads();
    int v = cnt[tid];
    int x = incl_scan256(v, sums4);
    binStart[tid] = x - v;
    __syncthreads();
    #pragma unroll
    for (int k = 0; k < 16; ++k){
        if (d[k] >= 0){
            int b = d[k] >> BSHIFT;
            int p = binStart[b] + atomicAdd(&binCur[b], 1);
            lp[p] = make_int2(s[k], d[k]);
        }
    }
    if (tid < NB){
        int c = cnt[tid];
        chunkBase[tid] = c ? atomicAdd(&bucketCur[tid], c) : 0;
    }
    __syncthreads();
    int total = min(CHUNK, E - base);
    for (int i = tid; i < total; i += 256){
        int2 p = lp[i];
        int b = p.y >> BSHIFT;
        pairs[chunkBase[b] + (i - binStart[b])] = p;
    }
}

__global__ __launch_bounds__(256) void k_hb_place(const int* __restrict__ hb, int N,
                                                  int* __restrict__ bincur,
                                                  int* __restrict__ nodes){
    __shared__ int cnt[256], binStart[256], binCur[256], chunkBase[256];
    __shared__ int sums4[4];
    __shared__ int lp[CHUNK];
    __shared__ unsigned char lb[CHUNK];
    int tid = threadIdx.x;
    cnt[tid] = 0; binCur[tid] = 0;
    __syncthreads();
    int base = blockIdx.x*CHUNK;
    int key[16];
    #pragma unroll
    for (int k = 0; k < 16; ++k){
        int i = base + k*256 + tid;
        key[k] = (i < N) ? hb[i] : -1;
        if (key[k] >= 0) atomicAdd(&cnt[key[k]], 1);
    }
    __syncthreads();
    int v = cnt[tid];
    int x = incl_scan256(v, sums4);
    binStart[tid] = x - v;
    __syncthreads();
    #pragma unroll
    for (int k = 0; k < 16; ++k){
        if (key[k] >= 0){
            int p = binStart[key[k]] + atomicAdd(&binCur[key[k]], 1);
            lp[p] = base + k*256 + tid;
            lb[p] = (unsigned char)key[k];
        }
    }
    if (cnt[tid]) chunkBase[tid] = atomicAdd(&bincur[tid], cnt[tid]);
    __syncthreads();
    int total = min(CHUNK, N - base);
    for (int i = tid; i < total; i += 256){
        int b = lb[i];
        nodes[chunkBase[b] + (i - binStart[b])] = lp[i];
    }
}

__global__ __launch_bounds__(256) void k_bucket_csr(const int2* __restrict__ pairs,
                                                    const int* __restrict__ bucketOff, int N,
                                                    int* __restrict__ rowptr,
                                                    int* __restrict__ colarr){
    __shared__ int deg[512], cur[512];
    __shared__ int sums4[4];
    __shared__ int tAs;
    int b = blockIdx.x, tid = threadIdx.x;
    int d0 = b << BSHIFT;
    int e0 = bucketOff[b], e1 = bucketOff[b+1];
    deg[tid] = 0; deg[256+tid] = 0;
    __syncthreads();
    for (int i = e0 + tid; i < e1; i += 256)
        atomicAdd(&deg[pairs[i].y - d0], 1);
    __syncthreads();
    int vA = deg[tid], vB = deg[256+tid];
    int xA = incl_scan256(vA, sums4);
    if (tid == 255) tAs = xA;
    int xB = incl_scan256(vB, sums4) + tAs;
    int exclA = xA - vA, exclB = xB - vB;
    cur[tid] = exclA; cur[256+tid] = exclB;
    int dA = d0 + tid, dB = d0 + 256 + tid;
    if (dA < N) rowptr[dA] = e0 + exclA;
    if (dB < N) rowptr[dB] = e0 + exclB;
    __syncthreads();
    for (int i = e0 + tid; i < e1; i += 256){
        int2 p = pairs[i];
        int pos = e0 + atomicAdd(&cur[p.y - d0], 1);
        colarr[pos] = p.x;
    }
}

// ---------------- transforms ----------------
__global__ __launch_bounds__(256) void k_transform_in(const float* __restrict__ x,
                                                      const float* __restrict__ W,  // [3][64]
                                                      const float* __restrict__ a_src,
                                                      const float* __restrict__ a_dst,
                                                      unsigned short* __restrict__ hout,  // rows of HROW
                                                      float* __restrict__ sdst, int N){
    int wv = blockIdx.x*4 + (threadIdx.x >> 6);
    int lane = threadIdx.x & 63;
    if (wv >= N) return;
    float acc = 0.f;
    #pragma unroll
    for (int k = 0; k < 3; ++k)
        acc += x[wv*3 + k] * W[k*64 + lane];
    hout[(size_t)wv*HROW + 8 + lane] = f2bf(acc);
    float v1 = acc * a_src[lane];
    float v2 = acc * a_dst[lane];
    #pragma unroll
    for (int o = 32; o; o >>= 1){ v1 += __shfl_xor(v1, o, 64); v2 += __shfl_xor(v2, o, 64); }
    if (lane == 0){
        *(float*)&hout[(size_t)wv*HROW] = v1;   // embedded ssrc
        sdst[wv] = v2;
    }
}

// MFMA transform: 64 rows/block; split-bf16 X@W ~= Xh@Wh + Xh@Wl + Xl@Wh.
#define LDW 72
__global__ __launch_bounds__(256) void k_transform_h_mfma(const float* __restrict__ feat,
                                                          const float* __restrict__ vn,      // [256][64] or null
                                                          const float* __restrict__ vn_emb,  // used if vn null
                                                          const int* __restrict__ hb,
                                                          const float* __restrict__ W,       // [64][64]
                                                          const float* __restrict__ a_src,
                                                          const float* __restrict__ a_dst,
                                                          unsigned short* __restrict__ hout, // rows of HROW
                                                          float* __restrict__ sdst, int N){
    __shared__ unsigned short WhT[64*LDW], WlT[64*LDW], Ah[64*LDW], Al[64*LDW];
    const int n0 = blockIdx.x * 64;

    for (int idx = threadIdx.x; idx < 4096; idx += 256){
        int n = idx >> 6, k = idx & 63;
        float w = W[k*64 + n];
        unsigned short hi = f2bf(w);
        WhT[n*LDW + k] = hi;
        WlT[n*LDW + k] = f2bf(w - bf2f(hi));
    }
    for (int t = threadIdx.x; t < 1024; t += 256){
        int row = t >> 4, c4 = t & 15;
        int node = n0 + row;
        float4 v = make_float4(0.f,0.f,0.f,0.f);
        if (node < N){
            v = ((const float4*)feat)[(size_t)node*16 + c4];
            float4 g = vn ? ((const float4*)vn)[(size_t)hb[node]*16 + c4]
                          : ((const float4*)vn_emb)[c4];
            v.x += g.x; v.y += g.y; v.z += g.z; v.w += g.w;
        }
        int base = row*LDW + c4*4;
        unsigned short h0 = f2bf(v.x), h1 = f2bf(v.y), h2 = f2bf(v.z), h3 = f2bf(v.w);
        Ah[base+0] = h0; Al[base+0] = f2bf(v.x - bf2f(h0));
        Ah[base+1] = h1; Al[base+1] = f2bf(v.y - bf2f(h1));
        Ah[base+2] = h2; Al[base+2] = f2bf(v.z - bf2f(h2));
        Ah[base+3] = h3; Al[base+3] = f2bf(v.w - bf2f(h3));
    }
    __syncthreads();

    int lane = threadIdx.x & 63;
    int wv   = threadIdx.x >> 6;
    int mrow = lane & 15, quad = lane >> 4;
    int m0 = wv * 16;

    f32x4 acc0 = {0,0,0,0}, acc1 = {0,0,0,0}, acc2 = {0,0,0,0}, acc3 = {0,0,0,0};
    #pragma unroll
    for (int k0 = 0; k0 < 64; k0 += 32){
        int kb = k0 + quad*8;
        short8 ah = *(const short8*)&Ah[(m0+mrow)*LDW + kb];
        short8 al = *(const short8*)&Al[(m0+mrow)*LDW + kb];
        short8 b0h = *(const short8*)&WhT[( 0+mrow)*LDW + kb];
        short8 b1h = *(const short8*)&WhT[(16+mrow)*LDW + kb];
        short8 b2h = *(const short8*)&WhT[(32+mrow)*LDW + kb];
        short8 b3h = *(const short8*)&WhT[(48+mrow)*LDW + kb];
        short8 b0l = *(const short8*)&WlT[( 0+mrow)*LDW + kb];
        short8 b1l = *(const short8*)&WlT[(16+mrow)*LDW + kb];
        short8 b2l = *(const short8*)&WlT[(32+mrow)*LDW + kb];
        short8 b3l = *(const short8*)&WlT[(48+mrow)*LDW + kb];
        acc0 = __builtin_amdgcn_mfma_f32_16x16x32_bf16(ah, b0h, acc0, 0, 0, 0);
        acc1 = __builtin_amdgcn_mfma_f32_16x16x32_bf16(ah, b1h, acc1, 0, 0, 0);
        acc2 = __builtin_amdgcn_mfma_f32_16x16x32_bf16(ah, b2h, acc2, 0, 0, 0);
        acc3 = __builtin_amdgcn_mfma_f32_16x16x32_bf16(ah, b3h, acc3, 0, 0, 0);
        acc0 = __builtin_amdgcn_mfma_f32_16x16x32_bf16(ah, b0l, acc0, 0, 0, 0);
        acc1 = __builtin_amdgcn_mfma_f32_16x16x32_bf16(ah, b1l, acc1, 0, 0, 0);
        acc2 = __builtin_amdgcn_mfma_f32_16x16x32_bf16(ah, b2l, acc2, 0, 0, 0);
        acc3 = __builtin_amdgcn_mfma_f32_16x16x32_bf16(ah, b3l, acc3, 0, 0, 0);
        acc0 = __builtin_amdgcn_mfma_f32_16x16x32_bf16(al, b0h, acc0, 0, 0, 0);
        acc1 = __builtin_amdgcn_mfma_f32_16x16x32_bf16(al, b1h, acc1, 0, 0, 0);
        acc2 = __builtin_amdgcn_mfma_f32_16x16x32_bf16(al, b2h, acc2, 0, 0, 0);
        acc3 = __builtin_amdgcn_mfma_f32_16x16x32_bf16(al, b3h, acc3, 0, 0, 0);
    }

    float as0 = a_src[mrow], as1 = a_src[16+mrow], as2 = a_src[32+mrow], as3 = a_src[48+mrow];
    float ad0 = a_dst[mrow], ad1 = a_dst[16+mrow], ad2 = a_dst[32+mrow], ad3 = a_dst[48+mrow];
    #pragma unroll
    for (int r = 0; r < 4; ++r){
        float p1 = acc0[r]*as0 + acc1[r]*as1 + acc2[r]*as2 + acc3[r]*as3;
        float p2 = acc0[r]*ad0 + acc1[r]*ad1 + acc2[r]*ad2 + acc3[r]*ad3;
        #pragma unroll
        for (int o = 8; o; o >>= 1){ p1 += __shfl_xor(p1, o, 64); p2 += __shfl_xor(p2, o, 64); }
        int node = n0 + m0 + quad*4 + r;
        if (mrow == 0 && node < N){
            *(float*)&hout[(size_t)node*HROW] = p1;   // embedded ssrc
            sdst[node] = p2;
        }
    }
    // restage C as bf16 into this wave's own Ah rows, then coalesced row stores
    #pragma unroll
    for (int r = 0; r < 4; ++r){
        int row = m0 + quad*4 + r;
        Ah[row*LDW + mrow     ] = f2bf(acc0[r]);
        Ah[row*LDW + mrow + 16] = f2bf(acc1[r]);
        Ah[row*LDW + mrow + 32] = f2bf(acc2[r]);
        Ah[row*LDW + mrow + 48] = f2bf(acc3[r]);
    }
    int r2 = lane >> 2, seg = lane & 3;
    int node = n0 + m0 + r2;
    if (node < N){
        short8 va = *(const short8*)&Ah[(m0+r2)*LDW + seg*16];
        short8 vb = *(const short8*)&Ah[(m0+r2)*LDW + seg*16 + 8];
        *(short8*)&hout[(size_t)node*HROW + 8 + seg*16]     = va;
        *(short8*)&hout[(size_t)node*HROW + 8 + seg*16 + 8] = vb;
    }
}

// ---------------- GAT aggregation ----------------
// One wave per dst. Softmax referenced to self-loop alpha. Phase A's ssrc
// gather (row head) warms the line phase B gathers. Phase B: 8 lanes/row,
// uint4 (16B) per lane, 8 rows in flight per step.
__global__ __launch_bounds__(256) void k_aggregate(const unsigned short* __restrict__ h,
                                                   const float* __restrict__ sdst,
                                                   const int* __restrict__ rowptr,
                                                   const int* __restrict__ col,
                                                   const float* __restrict__ bias,
                                                   float* __restrict__ out, int N){
    __shared__ float2 swb[4][64];
    int wv = threadIdx.x >> 6;
    int d = blockIdx.x*4 + wv;
    int lane = threadIdx.x & 63;
    if (d >= N) return;
    int r8 = lane >> 3, c8 = lane & 7;
    float sd = sdst[d];
    float a0 = *(const float*)&h[(size_t)d*HROW] + sd;
    a0 = (a0 < 0.f) ? 0.2f*a0 : a0;                            // self loop reference
    float dlocal = 0.f;
    float acc[8] = {0,0,0,0,0,0,0,0};
    if (r8 == 0){                                              // self loop, weight 1
        uint4 u = *(const uint4*)&h[(size_t)d*HROW + 8 + c8*8];
        acc[0] = __uint_as_float(u.x << 16); acc[1] = __uint_as_float(u.x & 0xffff0000u);
        acc[2] = __uint_as_float(u.y << 16); acc[3] = __uint_as_float(u.y & 0xffff0000u);
        acc[4] = __uint_as_float(u.z << 16); acc[5] = __uint_as_float(u.z & 0xffff0000u);
        acc[6] = __uint_as_float(u.w << 16); acc[7] = __uint_as_float(u.w & 0xffff0000u);
    }
    int e0 = rowptr[d], e1 = rowptr[d+1];
    for (int base = e0; base < e1; base += 64){
        int ne = min(64, e1 - base);
        float w = 0.f; int s = 0;
        if (lane < ne){
            s = col[base + lane];
            float a = *(const float*)&h[(size_t)s*HROW] + sd;   // warms the row's first line
            a = (a < 0.f) ? 0.2f*a : a;
            w = __expf(a - a0);
        }
        dlocal += w;
        swb[wv][lane] = make_float2(w, __int_as_float(s));
        int nj = (ne + 7) >> 3;
        for (int j = 0; j < nj; ++j){
            float2 p = swb[wv][j*8 + r8];        // w=0,s=0 for padded slots -> safe
            int sj = __float_as_int(p.y);
            uint4 u = *(const uint4*)&h[(size_t)sj*HROW + 8 + c8*8];
            acc[0] += p.x * __uint_as_float(u.x << 16);
            acc[1] += p.x * __uint_as_float(u.x & 0xffff0000u);
            acc[2] += p.x * __uint_as_float(u.y << 16);
            acc[3] += p.x * __uint_as_float(u.y & 0xffff0000u);
            acc[4] += p.x * __uint_as_float(u.z << 16);
            acc[5] += p.x * __uint_as_float(u.z & 0xffff0000u);
            acc[6] += p.x * __uint_as_float(u.w << 16);
            acc[7] += p.x * __uint_as_float(u.w & 0xffff0000u);
        }
    }
    #pragma unroll
    for (int o = 32; o; o >>= 1) dlocal += __shfl_xor(dlocal, o, 64);
    float denom = 1.0f + dlocal;
    #pragma unroll
    for (int o = 8; o <= 32; o <<= 1){
        #pragma unroll
        for (int k = 0; k < 8; ++k) acc[k] += __shfl_xor(acc[k], o, 64);
    }
    if (r8 == 0){
        float inv = 1.0f/denom;
        float4 b4a = ((const float4*)bias)[c8*2];
        float4 b4b = ((const float4*)bias)[c8*2 + 1];
        float4 o1 = make_float4(acc[0]*inv + b4a.x, acc[1]*inv + b4a.y,
                                acc[2]*inv + b4a.z, acc[3]*inv + b4a.w);
        float4 o2 = make_float4(acc[4]*inv + b4b.x, acc[5]*inv + b4b.y,
                                acc[6]*inv + b4b.z, acc[7]*inv + b4b.w);
        ((float4*)out)[(size_t)d*16 + c8*2    ] = o1;
        ((float4*)out)[(size_t)d*16 + c8*2 + 1] = o2;
    }
}

// ---------------- virtual-node stage ----------------
__global__ __launch_bounds__(256) void k_vn_segsum2(const float* __restrict__ outA,
                                                    const int* __restrict__ nodes,
                                                    const int* __restrict__ binptr,
                                                    float* __restrict__ vseg){   // [256*NSLICE][64]
    __shared__ float part[4][64];
    int b = blockIdx.x >> 3, s = blockIdx.x & (NSLICE-1);
    int wv = threadIdx.x >> 6, lane = threadIdx.x & 63;
    int i0 = binptr[b], i1 = binptr[b+1];
    int len = i1 - i0;
    int lo = i0 + (len*s)/NSLICE;
    int hi = i0 + (len*(s+1))/NSLICE;
    float acc = 0.f;
    for (int i = lo + wv; i < hi; i += 4){
        int n = nodes[i];
        acc += outA[(size_t)n*64 + lane];
    }
    part[wv][lane] = acc;
    __syncthreads();
    if (threadIdx.x < 64)
        vseg[(size_t)blockIdx.x*64 + lane] =
            part[0][lane] + part[1][lane] + part[2][lane] + part[3][lane];
}

__global__ __launch_bounds__(256) void k_vn_combine(const float* __restrict__ vseg,
                                                    const float* __restrict__ vd_old,
                                                    const float* __restrict__ root_old,
                                                    const float* __restrict__ vn_emb,
                                                    float* __restrict__ vw){   // [257][64]
    __shared__ float part[4][64];
    int wv = threadIdx.x >> 6, lane = threadIdx.x & 63;
    float rold = root_old ? root_old[lane] : vn_emb[lane];
    float emb  = vn_emb[lane];
    float csum = 0.f;
    for (int b = wv*64; b < wv*64 + 64; ++b){
        float v = 0.f;
        #pragma unroll
        for (int s = 0; s < NSLICE; ++s)
            v += vseg[(size_t)(b*NSLICE + s)*64 + lane];
        v += (vd_old ? vd_old[b*64 + lane] : emb) + rold;
        vw[b*64 + lane] = v;
        csum += v;
    }
    part[wv][lane] = csum;
    __syncthreads();
    if (threadIdx.x < 64)
        vw[256*64 + lane] = part[0][lane] + part[1][lane] + part[2][lane] + part[3][lane] + rold;
}

__global__ __launch_bounds__(256) void k_vn_mlp(const float* __restrict__ mlp_w1,
                                                const float* __restrict__ mlp_b1,
                                                const float* __restrict__ mlp_w2,
                                                const float* __restrict__ mlp_b2,
                                                int L, float* __restrict__ vw){
    __shared__ float Wl[64*64];
    int wv = blockIdx.x*4 + (threadIdx.x >> 6);
    int lane = threadIdx.x & 63;
    bool valid = (wv < 257);
    float iv = valid ? vw[wv*64 + lane] : 0.f;
    for (int m = 0; m < L; ++m){
        #pragma unroll
        for (int half = 0; half < 2; ++half){
            const float* W    = (half ? mlp_w2 : mlp_w1) + (size_t)m*4096;
            const float* bias = (half ? mlp_b2 : mlp_b1) + (size_t)m*64;
            __syncthreads();
            for (int i = threadIdx.x; i < 4096; i += 256) Wl[i] = W[i];
            __syncthreads();
            float acc = bias[lane];
            #pragma unroll
            for (int k = 0; k < 64; ++k)
                acc += __shfl(iv, k, 64) * Wl[k*64 + lane];
            iv = fmaxf(acc, 0.f);
        }
    }
    if (valid) vw[wv*64 + lane] = iv;
}

extern "C" void kernel_launch(void* const* d_in, const int* in_sizes, int n_in,
                              void* d_out, int out_size, void* d_ws, size_t ws_size,
                              hipStream_t stream) {
    const int N = in_sizes[0] / 3;
    const int E = in_sizes[1] / 2;
    const int L = in_sizes[9] / (64*64);
    const int NB = (N + (1<<BSHIFT) - 1) >> BSHIFT;

    const float* x        = (const float*)d_in[0];
    const int*   edge     = (const int*)d_in[1];
    const int*   srcp     = edge;
    const int*   dstp     = edge + E;
    const int*   hb       = (const int*)d_in[2];
    const float* w_in     = (const float*)d_in[5];
    const float* a_src_in = (const float*)d_in[6];
    const float* a_dst_in = (const float*)d_in[7];
    const float* b_in     = (const float*)d_in[8];
    const float* w_l      = (const float*)d_in[9];
    const float* a_src_l  = (const float*)d_in[10];
    const float* a_dst_l  = (const float*)d_in[11];
    const float* b_l      = (const float*)d_in[12];
    const float* mlp_w1   = (const float*)d_in[13];
    const float* mlp_b1   = (const float*)d_in[14];
    const float* mlp_w2   = (const float*)d_in[15];
    const float* mlp_b2   = (const float*)d_in[16];
    const float* vn_emb   = (const float*)d_in[17];
    float*       out      = (float*)d_out;

    // ---- workspace carve (256B-aligned) ----
    char* ws = (char*)d_ws;
    size_t off = 0;
    auto carve = [&](size_t bytes) -> char* {
        char* p = ws + off;
        off = (off + bytes + 255) & ~(size_t)255;
        return p;
    };
    unsigned short* h = (unsigned short*)carve((size_t)N*HROW*2);  // aliased as pairs in CSR build
    float* outA   = (float*)carve((size_t)N*64*4);
    float* sdst   = (float*)carve((size_t)N*4);
    int*   rowptr = (int*)carve((size_t)(N+1)*4);
    char*  zstart = ws + off;
    int*   bucketCount = (int*)carve(256*4);
    int*   hbBins = (int*)carve(256*4);
    size_t zbytes = (size_t)((ws + off) - zstart);
    int*   bucketOff = (int*)carve(257*4);
    int*   bucketCur = (int*)carve(256*4);
    int*   binptr = (int*)carve(257*4);
    int*   bincur = (int*)carve(256*4);
    int*   colarr = (int*)carve((size_t)E*4);
    int*   nodes  = (int*)carve((size_t)N*4);
    float* vseg   = (float*)carve((size_t)256*NSLICE*64*4);
    float* vw     = (float*)carve((size_t)257*64*4);
    if (off > ws_size) return;
    int2* pairs = (int2*)h;   // E*8 <= N*144 bytes; pairs dead before h's first write

    // ---- CSR + node-bin build ----
    hipMemsetAsync(zstart, 0, zbytes, stream);
    const int nchunkE = (E + CHUNK - 1) / CHUNK;
    const int nchunkN = (N + CHUNK - 1) / CHUNK;
    k_bucket_count<<<nchunkE, 256, 0, stream>>>(dstp, E, NB, bucketCount);
    k_hb_count    <<<nchunkN, 256, 0, stream>>>(hb, N, hbBins);
    k_scan_all    <<<1, 256, 0, stream>>>(bucketCount, NB, E, N, bucketOff, bucketCur, rowptr,
                                          hbBins, binptr, bincur);
    k_bucket_place<<<nchunkE, 256, 0, stream>>>(srcp, dstp, E, NB, bucketCur, pairs);
    k_bucket_csr  <<<NB, 256, 0, stream>>>(pairs, bucketOff, N, rowptr, colarr);
    k_hb_place    <<<nchunkN, 256, 0, stream>>>(hb, N, bincur, nodes);

    const int nwb = (N + 3) / 4;     // wave-per-node kernels
    const int nmb = (N + 63) / 64;   // mfma transform blocks

    // ---- GAT layer 0 (IN -> H) ----
    k_transform_in<<<nwb, 256, 0, stream>>>(x, w_in, a_src_in, a_dst_in, h, sdst, N);
    k_aggregate<<<nwb, 256, 0, stream>>>(h, sdst, rowptr, colarr, b_in, outA, N);

    // ---- hidden layers ----
    for (int l = 0; l < L; ++l){
        const float* vnp = (l == 0) ? nullptr : vw;
        k_transform_h_mfma<<<nmb, 256, 0, stream>>>(outA, vnp, vn_emb, hb,
                                                    w_l + (size_t)l*4096,
                                                    a_src_l + (size_t)l*64,
                                                    a_dst_l + (size_t)l*64,
                                                    h, sdst, N);
        const bool last = (l == L-1);
        float* dst_buf = last ? out : outA;
        k_aggregate<<<nwb, 256, 0, stream>>>(h, sdst, rowptr, colarr,
                                             b_l + (size_t)l*64, dst_buf, N);
        if (!last){
            const float* vdo = (l == 0) ? nullptr : vw;
            const float* ro  = (l == 0) ? nullptr : (vw + 256*64);
            k_vn_segsum2<<<256*NSLICE, 256, 0, stream>>>(outA, nodes, binptr, vseg);
            k_vn_combine<<<1, 256, 0, stream>>>(vseg, vdo, ro, vn_emb, vw);
            k_vn_mlp<<<(257+3)/4, 256, 0, stream>>>(mlp_w1, mlp_b1, mlp_w2, mlp_b2, L, vw);
        }
    }
}

// Round 9
// 373.067 us; speedup vs baseline: 1.1734x; 1.1734x over previous
//
#include <hip/hip_runtime.h>

// GNN with hierarchical virtual nodes. FP32 in/out, int32 indices.
//
//  CSR build: bucketed (dst>>9) two-level sort -> per-bucket-owned colarr.
//  Node list grouped by hb (counting sort) for the VN segment-sum.
//  h stored BF16 128B rows (64B-line aligned); ssrc/sdst separate fp32 arrays
//  (400KB -> L2-resident, gathers nearly free; R8 showed embedding them in the
//  row breaks alignment and costs +50MB of line traffic).
//  Aggregate: TWO dst per wave (32 lanes each) -- amortizes per-dst fixed cost
//  over avg degree 12; softmax referenced to self-loop alpha (shift-invariant).
//  (VN update after the last layer never reaches the output -> skipped)

typedef __attribute__((ext_vector_type(8))) short short8;
typedef __attribute__((ext_vector_type(4))) float f32x4;

__device__ __forceinline__ unsigned short f2bf(float x){      // RNE float->bf16
    unsigned u = __float_as_uint(x);
    unsigned r = (u + 0x7fffu + ((u >> 16) & 1u)) >> 16;
    return (unsigned short)r;
}
__device__ __forceinline__ float bf2f(unsigned short b){
    return __uint_as_float(((unsigned)b) << 16);
}

#define BSHIFT 9
#define CHUNK 4096
#define NSLICE 8

// inclusive scan of v across the 256 threads of the block (4 waves)
__device__ __forceinline__ int incl_scan256(int v, int* sums4){
    int lane = threadIdx.x & 63, w = threadIdx.x >> 6;
    int x = v;
    #pragma unroll
    for (int o = 1; o < 64; o <<= 1){ int t = __shfl_up(x, o, 64); if (lane >= o) x += t; }
    __syncthreads();
    if (lane == 63) sums4[w] = x;
    __syncthreads();
    for (int j = 0; j < w; ++j) x += sums4[j];
    return x;
}

// ---------------- bucketed CSR build ----------------
// fused: dst-bucket histogram over E and hb histogram over N
__global__ __launch_bounds__(256) void k_count(const int* __restrict__ dst, int E, int NB,
                                               int* __restrict__ bucketCount,
                                               const int* __restrict__ hb, int N,
                                               int* __restrict__ hbBins){
    __shared__ int cnt[256], cnt2[256];
    cnt[threadIdx.x] = 0; cnt2[threadIdx.x] = 0;
    __syncthreads();
    int base = blockIdx.x*CHUNK;
    int lim = min(base + CHUNK, E);
    for (int i = base + threadIdx.x; i < lim; i += 256)
        atomicAdd(&cnt[dst[i] >> BSHIFT], 1);
    int limN = min(base + CHUNK, N);
    for (int i = base + threadIdx.x; i < limN; i += 256)
        atomicAdd(&cnt2[hb[i]], 1);
    __syncthreads();
    if (threadIdx.x < NB && cnt[threadIdx.x])
        atomicAdd(&bucketCount[threadIdx.x], cnt[threadIdx.x]);
    if (cnt2[threadIdx.x])
        atomicAdd(&hbBins[threadIdx.x], cnt2[threadIdx.x]);
}

__global__ __launch_bounds__(256) void k_scan_all(const int* __restrict__ bucketCount,
                                                  int NB, int E, int N,
                                                  int* __restrict__ bucketOff,
                                                  int* __restrict__ bucketCur,
                                                  int* __restrict__ rowptr,
                                                  const int* __restrict__ hbBins,
                                                  int* __restrict__ binptr,
                                                  int* __restrict__ bincur){
    __shared__ int sums4[4];
    int tid = threadIdx.x;
    int v = (tid < NB) ? bucketCount[tid] : 0;
    int x = incl_scan256(v, sums4);
    if (tid < NB){ bucketOff[tid] = x - v; bucketCur[tid] = x - v; }
    if (tid == NB-1) bucketOff[NB] = x;
    if (tid == 0) rowptr[N] = E;
    int v2 = hbBins[tid];
    int x2 = incl_scan256(v2, sums4);
    binptr[tid] = x2 - v2;
    bincur[tid] = x2 - v2;
    if (tid == 255) binptr[256] = x2;
}

__global__ __launch_bounds__(256) void k_bucket_place(const int* __restrict__ src,
                                                      const int* __restrict__ dst, int E, int NB,
                                                      int* __restrict__ bucketCur,
                                                      int2* __restrict__ pairs){
    __shared__ int cnt[256], binStart[256], binCur[256], chunkBase[256];
    __shared__ int sums4[4];
    __shared__ int2 lp[CHUNK];
    int tid = threadIdx.x;
    cnt[tid] = 0; binCur[tid] = 0;
    __syncthreads();
    int base = blockIdx.x*CHUNK;
    int s[16], d[16];
    #pragma unroll
    for (int k = 0; k < 16; ++k){
        int i = base + k*256 + tid;
        if (i < E){ s[k] = src[i]; d[k] = dst[i]; atomicAdd(&cnt[d[k] >> BSHIFT], 1); }
        else d[k] = -1;
    }
    __syncthreads();
    int v = cnt[tid];
    int x = incl_scan256(v, sums4);
    binStart[tid] = x - v;
    __syncthreads();
    #pragma unroll
    for (int k = 0; k < 16; ++k){
        if (d[k] >= 0){
            int b = d[k] >> BSHIFT;
            int p = binStart[b] + atomicAdd(&binCur[b], 1);
            lp[p] = make_int2(s[k], d[k]);
        }
    }
    if (tid < NB){
        int c = cnt[tid];
        chunkBase[tid] = c ? atomicAdd(&bucketCur[tid], c) : 0;
    }
    __syncthreads();
    int total = min(CHUNK, E - base);
    for (int i = tid; i < total; i += 256){
        int2 p = lp[i];
        int b = p.y >> BSHIFT;
        pairs[chunkBase[b] + (i - binStart[b])] = p;
    }
}

__global__ __launch_bounds__(256) void k_hb_place(const int* __restrict__ hb, int N,
                                                  int* __restrict__ bincur,
                                                  int* __restrict__ nodes){
    __shared__ int cnt[256], binStart[256], binCur[256], chunkBase[256];
    __shared__ int sums4[4];
    __shared__ int lp[CHUNK];
    __shared__ unsigned char lb[CHUNK];
    int tid = threadIdx.x;
    cnt[tid] = 0; binCur[tid] = 0;
    __syncthreads();
    int base = blockIdx.x*CHUNK;
    int key[16];
    #pragma unroll
    for (int k = 0; k < 16; ++k){
        int i = base + k*256 + tid;
        key[k] = (i < N) ? hb[i] : -1;
        if (key[k] >= 0) atomicAdd(&cnt[key[k]], 1);
    }
    __syncthreads();
    int v = cnt[tid];
    int x = incl_scan256(v, sums4);
    binStart[tid] = x - v;
    __syncthreads();
    #pragma unroll
    for (int k = 0; k < 16; ++k){
        if (key[k] >= 0){
            int p = binStart[key[k]] + atomicAdd(&binCur[key[k]], 1);
            lp[p] = base + k*256 + tid;
            lb[p] = (unsigned char)key[k];
        }
    }
    if (cnt[tid]) chunkBase[tid] = atomicAdd(&bincur[tid], cnt[tid]);
    __syncthreads();
    int total = min(CHUNK, N - base);
    for (int i = tid; i < total; i += 256){
        int b = lb[i];
        nodes[chunkBase[b] + (i - binStart[b])] = lp[i];
    }
}

__global__ __launch_bounds__(256) void k_bucket_csr(const int2* __restrict__ pairs,
                                                    const int* __restrict__ bucketOff, int N,
                                                    int* __restrict__ rowptr,
                                                    int* __restrict__ colarr){
    __shared__ int deg[512], cur[512];
    __shared__ int sums4[4];
    __shared__ int tAs;
    int b = blockIdx.x, tid = threadIdx.x;
    int d0 = b << BSHIFT;
    int e0 = bucketOff[b], e1 = bucketOff[b+1];
    deg[tid] = 0; deg[256+tid] = 0;
    __syncthreads();
    for (int i = e0 + tid; i < e1; i += 256)
        atomicAdd(&deg[pairs[i].y - d0], 1);
    __syncthreads();
    int vA = deg[tid], vB = deg[256+tid];
    int xA = incl_scan256(vA, sums4);
    if (tid == 255) tAs = xA;
    int xB = incl_scan256(vB, sums4) + tAs;
    int exclA = xA - vA, exclB = xB - vB;
    cur[tid] = exclA; cur[256+tid] = exclB;
    int dA = d0 + tid, dB = d0 + 256 + tid;
    if (dA < N) rowptr[dA] = e0 + exclA;
    if (dB < N) rowptr[dB] = e0 + exclB;
    __syncthreads();
    for (int i = e0 + tid; i < e1; i += 256){
        int2 p = pairs[i];
        int pos = e0 + atomicAdd(&cur[p.y - d0], 1);
        colarr[pos] = p.x;
    }
}

// ---------------- transforms ----------------
__global__ __launch_bounds__(256) void k_transform_in(const float* __restrict__ x,
                                                      const float* __restrict__ W,  // [3][64]
                                                      const float* __restrict__ a_src,
                                                      const float* __restrict__ a_dst,
                                                      unsigned short* __restrict__ hout,  // bf16 64/row
                                                      float* __restrict__ ssrc,
                                                      float* __restrict__ sdst, int N){
    int wv = blockIdx.x*4 + (threadIdx.x >> 6);
    int lane = threadIdx.x & 63;
    if (wv >= N) return;
    float acc = 0.f;
    #pragma unroll
    for (int k = 0; k < 3; ++k)
        acc += x[wv*3 + k] * W[k*64 + lane];
    hout[(size_t)wv*64 + lane] = f2bf(acc);
    float v1 = acc * a_src[lane];
    float v2 = acc * a_dst[lane];
    #pragma unroll
    for (int o = 32; o; o >>= 1){ v1 += __shfl_xor(v1, o, 64); v2 += __shfl_xor(v2, o, 64); }
    if (lane == 0){ ssrc[wv] = v1; sdst[wv] = v2; }
}

// MFMA transform: 64 rows/block; split-bf16 X@W ~= Xh@Wh + Xh@Wl + Xl@Wh.
#define LDW 72
__global__ __launch_bounds__(256) void k_transform_h_mfma(const float* __restrict__ feat,
                                                          const float* __restrict__ vn,      // [256][64] or null
                                                          const float* __restrict__ vn_emb,  // used if vn null
                                                          const int* __restrict__ hb,
                                                          const float* __restrict__ W,       // [64][64]
                                                          const float* __restrict__ a_src,
                                                          const float* __restrict__ a_dst,
                                                          unsigned short* __restrict__ hout, // bf16 64/row
                                                          float* __restrict__ ssrc,
                                                          float* __restrict__ sdst, int N){
    __shared__ unsigned short WhT[64*LDW], WlT[64*LDW], Ah[64*LDW], Al[64*LDW];
    const int n0 = blockIdx.x * 64;

    for (int idx = threadIdx.x; idx < 4096; idx += 256){
        int n = idx >> 6, k = idx & 63;
        float w = W[k*64 + n];
        unsigned short hi = f2bf(w);
        WhT[n*LDW + k] = hi;
        WlT[n*LDW + k] = f2bf(w - bf2f(hi));
    }
    for (int t = threadIdx.x; t < 1024; t += 256){
        int row = t >> 4, c4 = t & 15;
        int node = n0 + row;
        float4 v = make_float4(0.f,0.f,0.f,0.f);
        if (node < N){
            v = ((const float4*)feat)[(size_t)node*16 + c4];
            float4 g = vn ? ((const float4*)vn)[(size_t)hb[node]*16 + c4]
                          : ((const float4*)vn_emb)[c4];
            v.x += g.x; v.y += g.y; v.z += g.z; v.w += g.w;
        }
        int base = row*LDW + c4*4;
        unsigned short h0 = f2bf(v.x), h1 = f2bf(v.y), h2 = f2bf(v.z), h3 = f2bf(v.w);
        Ah[base+0] = h0; Al[base+0] = f2bf(v.x - bf2f(h0));
        Ah[base+1] = h1; Al[base+1] = f2bf(v.y - bf2f(h1));
        Ah[base+2] = h2; Al[base+2] = f2bf(v.z - bf2f(h2));
        Ah[base+3] = h3; Al[base+3] = f2bf(v.w - bf2f(h3));
    }
    __syncthreads();

    int lane = threadIdx.x & 63;
    int wv   = threadIdx.x >> 6;
    int mrow = lane & 15, quad = lane >> 4;
    int m0 = wv * 16;

    f32x4 acc0 = {0,0,0,0}, acc1 = {0,0,0,0}, acc2 = {0,0,0,0}, acc3 = {0,0,0,0};
    #pragma unroll
    for (int k0 = 0; k0 < 64; k0 += 32){
        int kb = k0 + quad*8;
        short8 ah = *(const short8*)&Ah[(m0+mrow)*LDW + kb];
        short8 al = *(const short8*)&Al[(m0+mrow)*LDW + kb];
        short8 b0h = *(const short8*)&WhT[( 0+mrow)*LDW + kb];
        short8 b1h = *(const short8*)&WhT[(16+mrow)*LDW + kb];
        short8 b2h = *(const short8*)&WhT[(32+mrow)*LDW + kb];
        short8 b3h = *(const short8*)&WhT[(48+mrow)*LDW + kb];
        short8 b0l = *(const short8*)&WlT[( 0+mrow)*LDW + kb];
        short8 b1l = *(const short8*)&WlT[(16+mrow)*LDW + kb];
        short8 b2l = *(const short8*)&WlT[(32+mrow)*LDW + kb];
        short8 b3l = *(const short8*)&WlT[(48+mrow)*LDW + kb];
        acc0 = __builtin_amdgcn_mfma_f32_16x16x32_bf16(ah, b0h, acc0, 0, 0, 0);
        acc1 = __builtin_amdgcn_mfma_f32_16x16x32_bf16(ah, b1h, acc1, 0, 0, 0);
        acc2 = __builtin_amdgcn_mfma_f32_16x16x32_bf16(ah, b2h, acc2, 0, 0, 0);
        acc3 = __builtin_amdgcn_mfma_f32_16x16x32_bf16(ah, b3h, acc3, 0, 0, 0);
        acc0 = __builtin_amdgcn_mfma_f32_16x16x32_bf16(ah, b0l, acc0, 0, 0, 0);
        acc1 = __builtin_amdgcn_mfma_f32_16x16x32_bf16(ah, b1l, acc1, 0, 0, 0);
        acc2 = __builtin_amdgcn_mfma_f32_16x16x32_bf16(ah, b2l, acc2, 0, 0, 0);
        acc3 = __builtin_amdgcn_mfma_f32_16x16x32_bf16(ah, b3l, acc3, 0, 0, 0);
        acc0 = __builtin_amdgcn_mfma_f32_16x16x32_bf16(al, b0h, acc0, 0, 0, 0);
        acc1 = __builtin_amdgcn_mfma_f32_16x16x32_bf16(al, b1h, acc1, 0, 0, 0);
        acc2 = __builtin_amdgcn_mfma_f32_16x16x32_bf16(al, b2h, acc2, 0, 0, 0);
        acc3 = __builtin_amdgcn_mfma_f32_16x16x32_bf16(al, b3h, acc3, 0, 0, 0);
    }

    float as0 = a_src[mrow], as1 = a_src[16+mrow], as2 = a_src[32+mrow], as3 = a_src[48+mrow];
    float ad0 = a_dst[mrow], ad1 = a_dst[16+mrow], ad2 = a_dst[32+mrow], ad3 = a_dst[48+mrow];
    #pragma unroll
    for (int r = 0; r < 4; ++r){
        float p1 = acc0[r]*as0 + acc1[r]*as1 + acc2[r]*as2 + acc3[r]*as3;
        float p2 = acc0[r]*ad0 + acc1[r]*ad1 + acc2[r]*ad2 + acc3[r]*ad3;
        #pragma unroll
        for (int o = 8; o; o >>= 1){ p1 += __shfl_xor(p1, o, 64); p2 += __shfl_xor(p2, o, 64); }
        int node = n0 + m0 + quad*4 + r;
        if (mrow == 0 && node < N){ ssrc[node] = p1; sdst[node] = p2; }
    }
    // restage C as bf16 into this wave's own Ah rows, then coalesced row stores
    #pragma unroll
    for (int r = 0; r < 4; ++r){
        int row = m0 + quad*4 + r;
        Ah[row*LDW + mrow     ] = f2bf(acc0[r]);
        Ah[row*LDW + mrow + 16] = f2bf(acc1[r]);
        Ah[row*LDW + mrow + 32] = f2bf(acc2[r]);
        Ah[row*LDW + mrow + 48] = f2bf(acc3[r]);
    }
    int r2 = lane >> 2, seg = lane & 3;
    int node = n0 + m0 + r2;
    if (node < N){
        short8 va = *(const short8*)&Ah[(m0+r2)*LDW + seg*16];
        short8 vb = *(const short8*)&Ah[(m0+r2)*LDW + seg*16 + 8];
        *(short8*)&hout[(size_t)node*64 + seg*16]     = va;
        *(short8*)&hout[(size_t)node*64 + seg*16 + 8] = vb;
    }
}

// ---------------- GAT aggregation ----------------
// TWO dst per wave (32 lanes each). Softmax referenced to self-loop alpha.
// Phase A: 32 edge alphas (gathered L2-resident ssrc). Phase B: 8 lanes/row,
// uint4 (16B)/lane, 4 rows in flight per step. All reductions within the half.
__global__ __launch_bounds__(256) void k_aggregate(const unsigned short* __restrict__ h,
                                                   const float* __restrict__ ssrc,
                                                   const float* __restrict__ sdst,
                                                   const int* __restrict__ rowptr,
                                                   const int* __restrict__ col,
                                                   const float* __restrict__ bias,
                                                   float* __restrict__ out, int N){
    __shared__ float2 swb[4][64];
    int wv = threadIdx.x >> 6;
    int lane = threadIdx.x & 63;
    int half = lane >> 5, lane32 = lane & 31;
    int d = blockIdx.x*8 + wv*2 + half;
    if (d >= N) return;
    int r8 = lane32 >> 3, c8 = lane32 & 7;
    float sd = sdst[d];
    float a0 = ssrc[d] + sd; a0 = (a0 < 0.f) ? 0.2f*a0 : a0;   // self-loop reference
    float dlocal = 0.f;
    float acc[8] = {0,0,0,0,0,0,0,0};
    if (r8 == 0){                                              // self loop, weight 1
        uint4 u = *(const uint4*)&h[(size_t)d*64 + c8*8];
        acc[0] = __uint_as_float(u.x << 16); acc[1] = __uint_as_float(u.x & 0xffff0000u);
        acc[2] = __uint_as_float(u.y << 16); acc[3] = __uint_as_float(u.y & 0xffff0000u);
        acc[4] = __uint_as_float(u.z << 16); acc[5] = __uint_as_float(u.z & 0xffff0000u);
        acc[6] = __uint_as_float(u.w << 16); acc[7] = __uint_as_float(u.w & 0xffff0000u);
    }
    int e0 = rowptr[d], e1 = rowptr[d+1];
    for (int base = e0; base < e1; base += 32){
        int ne = min(32, e1 - base);
        float w = 0.f; int s = 0;
        if (lane32 < ne){
            s = col[base + lane32];
            float a = ssrc[s] + sd;                            // L2-resident gather
            a = (a < 0.f) ? 0.2f*a : a;
            w = __expf(a - a0);
        }
        dlocal += w;
        swb[wv][lane] = make_float2(w, __int_as_float(s));     // pad slots: w=0,s=0
        int nj = (ne + 3) >> 2;
        for (int j = 0; j < nj; ++j){
            float2 p = swb[wv][half*32 + j*4 + r8];
            int sj = __float_as_int(p.y);
            uint4 u = *(const uint4*)&h[(size_t)sj*64 + c8*8];
            acc[0] += p.x * __uint_as_float(u.x << 16);
            acc[1] += p.x * __uint_as_float(u.x & 0xffff0000u);
            acc[2] += p.x * __uint_as_float(u.y << 16);
            acc[3] += p.x * __uint_as_float(u.y & 0xffff0000u);
            acc[4] += p.x * __uint_as_float(u.z << 16);
            acc[5] += p.x * __uint_as_float(u.z & 0xffff0000u);
            acc[6] += p.x * __uint_as_float(u.w << 16);
            acc[7] += p.x * __uint_as_float(u.w & 0xffff0000u);
        }
    }
    // reductions confined to the 32-lane half (xor offsets <= 16)
    #pragma unroll
    for (int o = 16; o; o >>= 1) dlocal += __shfl_xor(dlocal, o, 64);
    float denom = 1.0f + dlocal;
    #pragma unroll
    for (int o = 8; o <= 16; o <<= 1){
        #pragma unroll
        for (int k = 0; k < 8; ++k) acc[k] += __shfl_xor(acc[k], o, 64);
    }
    if (r8 == 0){
        float inv = 1.0f/denom;
        float4 b4a = ((const float4*)bias)[c8*2];
        float4 b4b = ((const float4*)bias)[c8*2 + 1];
        float4 o1 = make_float4(acc[0]*inv + b4a.x, acc[1]*inv + b4a.y,
                                acc[2]*inv + b4a.z, acc[3]*inv + b4a.w);
        float4 o2 = make_float4(acc[4]*inv + b4b.x, acc[5]*inv + b4b.y,
                                acc[6]*inv + b4b.z, acc[7]*inv + b4b.w);
        ((float4*)out)[(size_t)d*16 + c8*2    ] = o1;
        ((float4*)out)[(size_t)d*16 + c8*2 + 1] = o2;
    }
}

// ---------------- virtual-node stage ----------------
__global__ __launch_bounds__(256) void k_vn_segsum2(const float* __restrict__ outA,
                                                    const int* __restrict__ nodes,
                                                    const int* __restrict__ binptr,
                                                    float* __restrict__ vseg){   // [256*NSLICE][64]
    __shared__ float part[4][64];
    int b = blockIdx.x >> 3, s = blockIdx.x & (NSLICE-1);
    int wv = threadIdx.x >> 6, lane = threadIdx.x & 63;
    int i0 = binptr[b], i1 = binptr[b+1];
    int len = i1 - i0;
    int lo = i0 + (len*s)/NSLICE;
    int hi = i0 + (len*(s+1))/NSLICE;
    float acc = 0.f;
    for (int i = lo + wv; i < hi; i += 4){
        int n = nodes[i];
        acc += outA[(size_t)n*64 + lane];
    }
    part[wv][lane] = acc;
    __syncthreads();
    if (threadIdx.x < 64)
        vseg[(size_t)blockIdx.x*64 + lane] =
            part[0][lane] + part[1][lane] + part[2][lane] + part[3][lane];
}

__global__ __launch_bounds__(256) void k_vn_combine(const float* __restrict__ vseg,
                                                    const float* __restrict__ vd_old,
                                                    const float* __restrict__ root_old,
                                                    const float* __restrict__ vn_emb,
                                                    float* __restrict__ vw){   // [257][64]
    __shared__ float part[4][64];
    int wv = threadIdx.x >> 6, lane = threadIdx.x & 63;
    float rold = root_old ? root_old[lane] : vn_emb[lane];
    float emb  = vn_emb[lane];
    float csum = 0.f;
    for (int b = wv*64; b < wv*64 + 64; ++b){
        float v = 0.f;
        #pragma unroll
        for (int s = 0; s < NSLICE; ++s)
            v += vseg[(size_t)(b*NSLICE + s)*64 + lane];
        v += (vd_old ? vd_old[b*64 + lane] : emb) + rold;
        vw[b*64 + lane] = v;
        csum += v;
    }
    part[wv][lane] = csum;
    __syncthreads();
    if (threadIdx.x < 64)
        vw[256*64 + lane] = part[0][lane] + part[1][lane] + part[2][lane] + part[3][lane] + rold;
}

__global__ __launch_bounds__(256) void k_vn_mlp(const float* __restrict__ mlp_w1,
                                                const float* __restrict__ mlp_b1,
                                                const float* __restrict__ mlp_w2,
                                                const float* __restrict__ mlp_b2,
                                                int L, float* __restrict__ vw){
    __shared__ float Wl[64*64];
    int wv = blockIdx.x*4 + (threadIdx.x >> 6);
    int lane = threadIdx.x & 63;
    bool valid = (wv < 257);
    float iv = valid ? vw[wv*64 + lane] : 0.f;
    for (int m = 0; m < L; ++m){
        #pragma unroll
        for (int half = 0; half < 2; ++half){
            const float* W    = (half ? mlp_w2 : mlp_w1) + (size_t)m*4096;
            const float* bias = (half ? mlp_b2 : mlp_b1) + (size_t)m*64;
            __syncthreads();
            for (int i = threadIdx.x; i < 4096; i += 256) Wl[i] = W[i];
            __syncthreads();
            float acc = bias[lane];
            #pragma unroll
            for (int k = 0; k < 64; ++k)
                acc += __shfl(iv, k, 64) * Wl[k*64 + lane];
            iv = fmaxf(acc, 0.f);
        }
    }
    if (valid) vw[wv*64 + lane] = iv;
}

extern "C" void kernel_launch(void* const* d_in, const int* in_sizes, int n_in,
                              void* d_out, int out_size, void* d_ws, size_t ws_size,
                              hipStream_t stream) {
    const int N = in_sizes[0] / 3;
    const int E = in_sizes[1] / 2;
    const int L = in_sizes[9] / (64*64);
    const int NB = (N + (1<<BSHIFT) - 1) >> BSHIFT;

    const float* x        = (const float*)d_in[0];
    const int*   edge     = (const int*)d_in[1];
    const int*   srcp     = edge;
    const int*   dstp     = edge + E;
    const int*   hb       = (const int*)d_in[2];
    const float* w_in     = (const float*)d_in[5];
    const float* a_src_in = (const float*)d_in[6];
    const float* a_dst_in = (const float*)d_in[7];
    const float* b_in     = (const float*)d_in[8];
    const float* w_l      = (const float*)d_in[9];
    const float* a_src_l  = (const float*)d_in[10];
    const float* a_dst_l  = (const float*)d_in[11];
    const float* b_l      = (const float*)d_in[12];
    const float* mlp_w1   = (const float*)d_in[13];
    const float* mlp_b1   = (const float*)d_in[14];
    const float* mlp_w2   = (const float*)d_in[15];
    const float* mlp_b2   = (const float*)d_in[16];
    const float* vn_emb   = (const float*)d_in[17];
    float*       out      = (float*)d_out;

    // ---- workspace carve (256B-aligned) ----
    char* ws = (char*)d_ws;
    size_t off = 0;
    auto carve = [&](size_t bytes) -> char* {
        char* p = ws + off;
        off = (off + bytes + 255) & ~(size_t)255;
        return p;
    };
    unsigned short* h = (unsigned short*)carve((size_t)N*64*2);  // aliased as pairs in CSR build
    float* outA   = (float*)carve((size_t)N*64*4);
    float* ssrc   = (float*)carve((size_t)N*4);
    float* sdst   = (float*)carve((size_t)N*4);
    int*   rowptr = (int*)carve((size_t)(N+1)*4);
    char*  zstart = ws + off;
    int*   bucketCount = (int*)carve(256*4);
    int*   hbBins = (int*)carve(256*4);
    size_t zbytes = (size_t)((ws + off) - zstart);
    int*   bucketOff = (int*)carve(257*4);
    int*   bucketCur = (int*)carve(256*4);
    int*   binptr = (int*)carve(257*4);
    int*   bincur = (int*)carve(256*4);
    int*   colarr = (int*)carve((size_t)E*4);
    int*   nodes  = (int*)carve((size_t)N*4);
    float* vseg   = (float*)carve((size_t)256*NSLICE*64*4);
    float* vw     = (float*)carve((size_t)257*64*4);
    if (off > ws_size) return;
    int2* pairs = (int2*)h;   // E*8 <= N*128 bytes; pairs dead before h's first write

    // ---- CSR + node-bin build ----
    hipMemsetAsync(zstart, 0, zbytes, stream);
    const int nchunkE = (E + CHUNK - 1) / CHUNK;
    const int nchunkN = (N + CHUNK - 1) / CHUNK;
    k_count       <<<nchunkE, 256, 0, stream>>>(dstp, E, NB, bucketCount, hb, N, hbBins);
    k_scan_all    <<<1, 256, 0, stream>>>(bucketCount, NB, E, N, bucketOff, bucketCur, rowptr,
                                          hbBins, binptr, bincur);
    k_bucket_place<<<nchunkE, 256, 0, stream>>>(srcp, dstp, E, NB, bucketCur, pairs);
    k_bucket_csr  <<<NB, 256, 0, stream>>>(pairs, bucketOff, N, rowptr, colarr);
    k_hb_place    <<<nchunkN, 256, 0, stream>>>(hb, N, bincur, nodes);

    const int nwb = (N + 3) / 4;     // wave-per-node kernels
    const int nab = (N + 7) / 8;     // aggregate: 2 dst/wave, 8 dst/block
    const int nmb = (N + 63) / 64;   // mfma transform blocks

    // ---- GAT layer 0 (IN -> H) ----
    k_transform_in<<<nwb, 256, 0, stream>>>(x, w_in, a_src_in, a_dst_in, h, ssrc, sdst, N);
    k_aggregate<<<nab, 256, 0, stream>>>(h, ssrc, sdst, rowptr, colarr, b_in, outA, N);

    // ---- hidden layers ----
    for (int l = 0; l < L; ++l){
        const float* vnp = (l == 0) ? nullptr : vw;
        k_transform_h_mfma<<<nmb, 256, 0, stream>>>(outA, vnp, vn_emb, hb,
                                                    w_l + (size_t)l*4096,
                                                    a_src_l + (size_t)l*64,
                                                    a_dst_l + (size_t)l*64,
                                                    h, ssrc, sdst, N);
        const bool last = (l == L-1);
        float* dst_buf = last ? out : outA;
        k_aggregate<<<nab, 256, 0, stream>>>(h, ssrc, sdst, rowptr, colarr,
                                             b_l + (size_t)l*64, dst_buf, N);
        if (!last){
            const float* vdo = (l == 0) ? nullptr : vw;
            const float* ro  = (l == 0) ? nullptr : (vw + 256*64);
            k_vn_segsum2<<<256*NSLICE, 256, 0, stream>>>(outA, nodes, binptr, vseg);
            k_vn_combine<<<1, 256, 0, stream>>>(vseg, vdo, ro, vn_emb, vw);
            k_vn_mlp<<<(257+3)/4, 256, 0, stream>>>(mlp_w1, mlp_b1, mlp_w2, mlp_b2, L, vw);
        }
    }
}

// Round 10
// 360.246 us; speedup vs baseline: 1.2151x; 1.0356x over previous
//
#include <hip/hip_runtime.h>

// GNN with hierarchical virtual nodes. FP32 in/out, int32 indices.
//
//  CSR build: bucketed (dst>>9) two-level sort -> per-bucket-owned colarr.
//  Node list grouped by hb (counting sort) for the VN segment-sum.
//  h stored BF16 128B rows (64B-line aligned); ssrc/sdst separate fp32 arrays
//  (L2-resident; R8 showed embedding them in the row breaks alignment, +50MB).
//  Aggregate: TWO dst per wave (32 lanes each), phase-B gathers manually
//  unrolled x2 (8 rows in flight) for memory-level parallelism.
//  Softmax referenced to self-loop alpha (shift-invariant).
//  (VN update after the last layer never reaches the output -> skipped)

typedef __attribute__((ext_vector_type(8))) short short8;
typedef __attribute__((ext_vector_type(4))) float f32x4;

__device__ __forceinline__ unsigned short f2bf(float x){      // RNE float->bf16
    unsigned u = __float_as_uint(x);
    unsigned r = (u + 0x7fffu + ((u >> 16) & 1u)) >> 16;
    return (unsigned short)r;
}
__device__ __forceinline__ float bf2f(unsigned short b){
    return __uint_as_float(((unsigned)b) << 16);
}

#define BSHIFT 9
#define CHUNK 4096
#define NSLICE 8

// inclusive scan of v across the 256 threads of the block (4 waves)
__device__ __forceinline__ int incl_scan256(int v, int* sums4){
    int lane = threadIdx.x & 63, w = threadIdx.x >> 6;
    int x = v;
    #pragma unroll
    for (int o = 1; o < 64; o <<= 1){ int t = __shfl_up(x, o, 64); if (lane >= o) x += t; }
    __syncthreads();
    if (lane == 63) sums4[w] = x;
    __syncthreads();
    for (int j = 0; j < w; ++j) x += sums4[j];
    return x;
}

// ---------------- bucketed CSR build ----------------
__global__ __launch_bounds__(256) void k_count(const int* __restrict__ dst, int E, int NB,
                                               int* __restrict__ bucketCount,
                                               const int* __restrict__ hb, int N,
                                               int* __restrict__ hbBins){
    __shared__ int cnt[256], cnt2[256];
    cnt[threadIdx.x] = 0; cnt2[threadIdx.x] = 0;
    __syncthreads();
    int base = blockIdx.x*CHUNK;
    int lim = min(base + CHUNK, E);
    for (int i = base + threadIdx.x; i < lim; i += 256)
        atomicAdd(&cnt[dst[i] >> BSHIFT], 1);
    int limN = min(base + CHUNK, N);
    for (int i = base + threadIdx.x; i < limN; i += 256)
        atomicAdd(&cnt2[hb[i]], 1);
    __syncthreads();
    if (threadIdx.x < NB && cnt[threadIdx.x])
        atomicAdd(&bucketCount[threadIdx.x], cnt[threadIdx.x]);
    if (cnt2[threadIdx.x])
        atomicAdd(&hbBins[threadIdx.x], cnt2[threadIdx.x]);
}

__global__ __launch_bounds__(256) void k_scan_all(const int* __restrict__ bucketCount,
                                                  int NB, int E, int N,
                                                  int* __restrict__ bucketOff,
                                                  int* __restrict__ bucketCur,
                                                  int* __restrict__ rowptr,
                                                  const int* __restrict__ hbBins,
                                                  int* __restrict__ binptr,
                                                  int* __restrict__ bincur){
    __shared__ int sums4[4];
    int tid = threadIdx.x;
    int v = (tid < NB) ? bucketCount[tid] : 0;
    int x = incl_scan256(v, sums4);
    if (tid < NB){ bucketOff[tid] = x - v; bucketCur[tid] = x - v; }
    if (tid == NB-1) bucketOff[NB] = x;
    if (tid == 0) rowptr[N] = E;
    int v2 = hbBins[tid];
    int x2 = incl_scan256(v2, sums4);
    binptr[tid] = x2 - v2;
    bincur[tid] = x2 - v2;
    if (tid == 255) binptr[256] = x2;
}

__global__ __launch_bounds__(256) void k_bucket_place(const int* __restrict__ src,
                                                      const int* __restrict__ dst, int E, int NB,
                                                      int* __restrict__ bucketCur,
                                                      int2* __restrict__ pairs){
    __shared__ int cnt[256], binStart[256], binCur[256], chunkBase[256];
    __shared__ int sums4[4];
    __shared__ int2 lp[CHUNK];
    int tid = threadIdx.x;
    cnt[tid] = 0; binCur[tid] = 0;
    __syncthreads();
    int base = blockIdx.x*CHUNK;
    int s[16], d[16];
    #pragma unroll
    for (int k = 0; k < 16; ++k){
        int i = base + k*256 + tid;
        if (i < E){ s[k] = src[i]; d[k] = dst[i]; atomicAdd(&cnt[d[k] >> BSHIFT], 1); }
        else d[k] = -1;
    }
    __syncthreads();
    int v = cnt[tid];
    int x = incl_scan256(v, sums4);
    binStart[tid] = x - v;
    __syncthreads();
    #pragma unroll
    for (int k = 0; k < 16; ++k){
        if (d[k] >= 0){
            int b = d[k] >> BSHIFT;
            int p = binStart[b] + atomicAdd(&binCur[b], 1);
            lp[p] = make_int2(s[k], d[k]);
        }
    }
    if (tid < NB){
        int c = cnt[tid];
        chunkBase[tid] = c ? atomicAdd(&bucketCur[tid], c) : 0;
    }
    __syncthreads();
    int total = min(CHUNK, E - base);
    for (int i = tid; i < total; i += 256){
        int2 p = lp[i];
        int b = p.y >> BSHIFT;
        pairs[chunkBase[b] + (i - binStart[b])] = p;
    }
}

__global__ __launch_bounds__(256) void k_hb_place(const int* __restrict__ hb, int N,
                                                  int* __restrict__ bincur,
                                                  int* __restrict__ nodes){
    __shared__ int cnt[256], binStart[256], binCur[256], chunkBase[256];
    __shared__ int sums4[4];
    __shared__ int lp[CHUNK];
    __shared__ unsigned char lb[CHUNK];
    int tid = threadIdx.x;
    cnt[tid] = 0; binCur[tid] = 0;
    __syncthreads();
    int base = blockIdx.x*CHUNK;
    int key[16];
    #pragma unroll
    for (int k = 0; k < 16; ++k){
        int i = base + k*256 + tid;
        key[k] = (i < N) ? hb[i] : -1;
        if (key[k] >= 0) atomicAdd(&cnt[key[k]], 1);
    }
    __syncthreads();
    int v = cnt[tid];
    int x = incl_scan256(v, sums4);
    binStart[tid] = x - v;
    __syncthreads();
    #pragma unroll
    for (int k = 0; k < 16; ++k){
        if (key[k] >= 0){
            int p = binStart[key[k]] + atomicAdd(&binCur[key[k]], 1);
            lp[p] = base + k*256 + tid;
            lb[p] = (unsigned char)key[k];
        }
    }
    if (cnt[tid]) chunkBase[tid] = atomicAdd(&bincur[tid], cnt[tid]);
    __syncthreads();
    int total = min(CHUNK, N - base);
    for (int i = tid; i < total; i += 256){
        int b = lb[i];
        nodes[chunkBase[b] + (i - binStart[b])] = lp[i];
    }
}

__global__ __launch_bounds__(256) void k_bucket_csr(const int2* __restrict__ pairs,
                                                    const int* __restrict__ bucketOff, int N,
                                                    int* __restrict__ rowptr,
                                                    int* __restrict__ colarr){
    __shared__ int deg[512], cur[512];
    __shared__ int sums4[4];
    __shared__ int tAs;
    int b = blockIdx.x, tid = threadIdx.x;
    int d0 = b << BSHIFT;
    int e0 = bucketOff[b], e1 = bucketOff[b+1];
    deg[tid] = 0; deg[256+tid] = 0;
    __syncthreads();
    for (int i = e0 + tid; i < e1; i += 256)
        atomicAdd(&deg[pairs[i].y - d0], 1);
    __syncthreads();
    int vA = deg[tid], vB = deg[256+tid];
    int xA = incl_scan256(vA, sums4);
    if (tid == 255) tAs = xA;
    int xB = incl_scan256(vB, sums4) + tAs;
    int exclA = xA - vA, exclB = xB - vB;
    cur[tid] = exclA; cur[256+tid] = exclB;
    int dA = d0 + tid, dB = d0 + 256 + tid;
    if (dA < N) rowptr[dA] = e0 + exclA;
    if (dB < N) rowptr[dB] = e0 + exclB;
    __syncthreads();
    for (int i = e0 + tid; i < e1; i += 256){
        int2 p = pairs[i];
        int pos = e0 + atomicAdd(&cur[p.y - d0], 1);
        colarr[pos] = p.x;
    }
}

// ---------------- transforms ----------------
__global__ __launch_bounds__(256) void k_transform_in(const float* __restrict__ x,
                                                      const float* __restrict__ W,  // [3][64]
                                                      const float* __restrict__ a_src,
                                                      const float* __restrict__ a_dst,
                                                      unsigned short* __restrict__ hout,  // bf16 64/row
                                                      float* __restrict__ ssrc,
                                                      float* __restrict__ sdst, int N){
    int wv = blockIdx.x*4 + (threadIdx.x >> 6);
    int lane = threadIdx.x & 63;
    if (wv >= N) return;
    float acc = 0.f;
    #pragma unroll
    for (int k = 0; k < 3; ++k)
        acc += x[wv*3 + k] * W[k*64 + lane];
    hout[(size_t)wv*64 + lane] = f2bf(acc);
    float v1 = acc * a_src[lane];
    float v2 = acc * a_dst[lane];
    #pragma unroll
    for (int o = 32; o; o >>= 1){ v1 += __shfl_xor(v1, o, 64); v2 += __shfl_xor(v2, o, 64); }
    if (lane == 0){ ssrc[wv] = v1; sdst[wv] = v2; }
}

// MFMA transform: 64 rows/block; split-bf16 X@W ~= Xh@Wh + Xh@Wl + Xl@Wh.
#define LDW 72
__global__ __launch_bounds__(256) void k_transform_h_mfma(const float* __restrict__ feat,
                                                          const float* __restrict__ vn,      // [256][64] or null
                                                          const float* __restrict__ vn_emb,  // used if vn null
                                                          const int* __restrict__ hb,
                                                          const float* __restrict__ W,       // [64][64]
                                                          const float* __restrict__ a_src,
                                                          const float* __restrict__ a_dst,
                                                          unsigned short* __restrict__ hout, // bf16 64/row
                                                          float* __restrict__ ssrc,
                                                          float* __restrict__ sdst, int N){
    __shared__ unsigned short WhT[64*LDW], WlT[64*LDW], Ah[64*LDW], Al[64*LDW];
    const int n0 = blockIdx.x * 64;

    for (int idx = threadIdx.x; idx < 4096; idx += 256){
        int n = idx >> 6, k = idx & 63;
        float w = W[k*64 + n];
        unsigned short hi = f2bf(w);
        WhT[n*LDW + k] = hi;
        WlT[n*LDW + k] = f2bf(w - bf2f(hi));
    }
    for (int t = threadIdx.x; t < 1024; t += 256){
        int row = t >> 4, c4 = t & 15;
        int node = n0 + row;
        float4 v = make_float4(0.f,0.f,0.f,0.f);
        if (node < N){
            v = ((const float4*)feat)[(size_t)node*16 + c4];
            float4 g = vn ? ((const float4*)vn)[(size_t)hb[node]*16 + c4]
                          : ((const float4*)vn_emb)[c4];
            v.x += g.x; v.y += g.y; v.z += g.z; v.w += g.w;
        }
        int base = row*LDW + c4*4;
        unsigned short h0 = f2bf(v.x), h1 = f2bf(v.y), h2 = f2bf(v.z), h3 = f2bf(v.w);
        Ah[base+0] = h0; Al[base+0] = f2bf(v.x - bf2f(h0));
        Ah[base+1] = h1; Al[base+1] = f2bf(v.y - bf2f(h1));
        Ah[base+2] = h2; Al[base+2] = f2bf(v.z - bf2f(h2));
        Ah[base+3] = h3; Al[base+3] = f2bf(v.w - bf2f(h3));
    }
    __syncthreads();

    int lane = threadIdx.x & 63;
    int wv   = threadIdx.x >> 6;
    int mrow = lane & 15, quad = lane >> 4;
    int m0 = wv * 16;

    f32x4 acc0 = {0,0,0,0}, acc1 = {0,0,0,0}, acc2 = {0,0,0,0}, acc3 = {0,0,0,0};
    #pragma unroll
    for (int k0 = 0; k0 < 64; k0 += 32){
        int kb = k0 + quad*8;
        short8 ah = *(const short8*)&Ah[(m0+mrow)*LDW + kb];
        short8 al = *(const short8*)&Al[(m0+mrow)*LDW + kb];
        short8 b0h = *(const short8*)&WhT[( 0+mrow)*LDW + kb];
        short8 b1h = *(const short8*)&WhT[(16+mrow)*LDW + kb];
        short8 b2h = *(const short8*)&WhT[(32+mrow)*LDW + kb];
        short8 b3h = *(const short8*)&WhT[(48+mrow)*LDW + kb];
        short8 b0l = *(const short8*)&WlT[( 0+mrow)*LDW + kb];
        short8 b1l = *(const short8*)&WlT[(16+mrow)*LDW + kb];
        short8 b2l = *(const short8*)&WlT[(32+mrow)*LDW + kb];
        short8 b3l = *(const short8*)&WlT[(48+mrow)*LDW + kb];
        acc0 = __builtin_amdgcn_mfma_f32_16x16x32_bf16(ah, b0h, acc0, 0, 0, 0);
        acc1 = __builtin_amdgcn_mfma_f32_16x16x32_bf16(ah, b1h, acc1, 0, 0, 0);
        acc2 = __builtin_amdgcn_mfma_f32_16x16x32_bf16(ah, b2h, acc2, 0, 0, 0);
        acc3 = __builtin_amdgcn_mfma_f32_16x16x32_bf16(ah, b3h, acc3, 0, 0, 0);
        acc0 = __builtin_amdgcn_mfma_f32_16x16x32_bf16(ah, b0l, acc0, 0, 0, 0);
        acc1 = __builtin_amdgcn_mfma_f32_16x16x32_bf16(ah, b1l, acc1, 0, 0, 0);
        acc2 = __builtin_amdgcn_mfma_f32_16x16x32_bf16(ah, b2l, acc2, 0, 0, 0);
        acc3 = __builtin_amdgcn_mfma_f32_16x16x32_bf16(ah, b3l, acc3, 0, 0, 0);
        acc0 = __builtin_amdgcn_mfma_f32_16x16x32_bf16(al, b0h, acc0, 0, 0, 0);
        acc1 = __builtin_amdgcn_mfma_f32_16x16x32_bf16(al, b1h, acc1, 0, 0, 0);
        acc2 = __builtin_amdgcn_mfma_f32_16x16x32_bf16(al, b2h, acc2, 0, 0, 0);
        acc3 = __builtin_amdgcn_mfma_f32_16x16x32_bf16(al, b3h, acc3, 0, 0, 0);
    }

    float as0 = a_src[mrow], as1 = a_src[16+mrow], as2 = a_src[32+mrow], as3 = a_src[48+mrow];
    float ad0 = a_dst[mrow], ad1 = a_dst[16+mrow], ad2 = a_dst[32+mrow], ad3 = a_dst[48+mrow];
    #pragma unroll
    for (int r = 0; r < 4; ++r){
        float p1 = acc0[r]*as0 + acc1[r]*as1 + acc2[r]*as2 + acc3[r]*as3;
        float p2 = acc0[r]*ad0 + acc1[r]*ad1 + acc2[r]*ad2 + acc3[r]*ad3;
        #pragma unroll
        for (int o = 8; o; o >>= 1){ p1 += __shfl_xor(p1, o, 64); p2 += __shfl_xor(p2, o, 64); }
        int node = n0 + m0 + quad*4 + r;
        if (mrow == 0 && node < N){ ssrc[node] = p1; sdst[node] = p2; }
    }
    // restage C as bf16 into this wave's own Ah rows, then coalesced row stores
    #pragma unroll
    for (int r = 0; r < 4; ++r){
        int row = m0 + quad*4 + r;
        Ah[row*LDW + mrow     ] = f2bf(acc0[r]);
        Ah[row*LDW + mrow + 16] = f2bf(acc1[r]);
        Ah[row*LDW + mrow + 32] = f2bf(acc2[r]);
        Ah[row*LDW + mrow + 48] = f2bf(acc3[r]);
    }
    int r2 = lane >> 2, seg = lane & 3;
    int node = n0 + m0 + r2;
    if (node < N){
        short8 va = *(const short8*)&Ah[(m0+r2)*LDW + seg*16];
        short8 vb = *(const short8*)&Ah[(m0+r2)*LDW + seg*16 + 8];
        *(short8*)&hout[(size_t)node*64 + seg*16]     = va;
        *(short8*)&hout[(size_t)node*64 + seg*16 + 8] = vb;
    }
}

// ---------------- GAT aggregation ----------------
// TWO dst per wave (32 lanes each). Softmax referenced to self-loop alpha.
// Phase B: 8 lanes/row, uint4/lane, manually unrolled x2 -> 8 rows in flight.
__global__ __launch_bounds__(256) void k_aggregate(const unsigned short* __restrict__ h,
                                                   const float* __restrict__ ssrc,
                                                   const float* __restrict__ sdst,
                                                   const int* __restrict__ rowptr,
                                                   const int* __restrict__ col,
                                                   const float* __restrict__ bias,
                                                   float* __restrict__ out, int N){
    __shared__ float2 swb[4][64];
    int wv = threadIdx.x >> 6;
    int lane = threadIdx.x & 63;
    int half = lane >> 5, lane32 = lane & 31;
    int d = blockIdx.x*8 + wv*2 + half;
    if (d >= N) return;
    int r8 = lane32 >> 3, c8 = lane32 & 7;
    float sd = sdst[d];
    float a0 = ssrc[d] + sd; a0 = (a0 < 0.f) ? 0.2f*a0 : a0;   // self-loop reference
    float dlocal = 0.f;
    float acc[8] = {0,0,0,0,0,0,0,0};
    if (r8 == 0){                                              // self loop, weight 1
        uint4 u = *(const uint4*)&h[(size_t)d*64 + c8*8];
        acc[0] = __uint_as_float(u.x << 16); acc[1] = __uint_as_float(u.x & 0xffff0000u);
        acc[2] = __uint_as_float(u.y << 16); acc[3] = __uint_as_float(u.y & 0xffff0000u);
        acc[4] = __uint_as_float(u.z << 16); acc[5] = __uint_as_float(u.z & 0xffff0000u);
        acc[6] = __uint_as_float(u.w << 16); acc[7] = __uint_as_float(u.w & 0xffff0000u);
    }
    int e0 = rowptr[d], e1 = rowptr[d+1];
    for (int base = e0; base < e1; base += 32){
        int ne = min(32, e1 - base);
        float w = 0.f; int s = 0;
        if (lane32 < ne){
            s = col[base + lane32];
            float a = ssrc[s] + sd;                            // L2-resident gather
            a = (a < 0.f) ? 0.2f*a : a;
            w = __expf(a - a0);
        }
        dlocal += w;
        swb[wv][lane] = make_float2(w, __int_as_float(s));     // pad slots: w=0,s=0
        int nj = (ne + 3) >> 2;                                // steps of 4 rows
        for (int j = 0; j < nj; j += 2){                       // x2 unroll: 8 rows in flight
            float2 p0 = swb[wv][half*32 + j*4 + r8];
            float2 p1 = swb[wv][half*32 + j*4 + 4 + r8];       // always fresh; w=0 pad safe
            int s0 = __float_as_int(p0.y);
            int s1 = __float_as_int(p1.y);
            uint4 u0 = *(const uint4*)&h[(size_t)s0*64 + c8*8];
            uint4 u1 = *(const uint4*)&h[(size_t)s1*64 + c8*8];
            acc[0] += p0.x * __uint_as_float(u0.x << 16);
            acc[1] += p0.x * __uint_as_float(u0.x & 0xffff0000u);
            acc[2] += p0.x * __uint_as_float(u0.y << 16);
            acc[3] += p0.x * __uint_as_float(u0.y & 0xffff0000u);
            acc[4] += p0.x * __uint_as_float(u0.z << 16);
            acc[5] += p0.x * __uint_as_float(u0.z & 0xffff0000u);
            acc[6] += p0.x * __uint_as_float(u0.w << 16);
            acc[7] += p0.x * __uint_as_float(u0.w & 0xffff0000u);
            acc[0] += p1.x * __uint_as_float(u1.x << 16);
            acc[1] += p1.x * __uint_as_float(u1.x & 0xffff0000u);
            acc[2] += p1.x * __uint_as_float(u1.y << 16);
            acc[3] += p1.x * __uint_as_float(u1.y & 0xffff0000u);
            acc[4] += p1.x * __uint_as_float(u1.z << 16);
            acc[5] += p1.x * __uint_as_float(u1.z & 0xffff0000u);
            acc[6] += p1.x * __uint_as_float(u1.w << 16);
            acc[7] += p1.x * __uint_as_float(u1.w & 0xffff0000u);
        }
    }
    // reductions confined to the 32-lane half (xor offsets <= 16)
    #pragma unroll
    for (int o = 16; o; o >>= 1) dlocal += __shfl_xor(dlocal, o, 64);
    float denom = 1.0f + dlocal;
    #pragma unroll
    for (int o = 8; o <= 16; o <<= 1){
        #pragma unroll
        for (int k = 0; k < 8; ++k) acc[k] += __shfl_xor(acc[k], o, 64);
    }
    if (r8 == 0){
        float inv = 1.0f/denom;
        float4 b4a = ((const float4*)bias)[c8*2];
        float4 b4b = ((const float4*)bias)[c8*2 + 1];
        float4 o1 = make_float4(acc[0]*inv + b4a.x, acc[1]*inv + b4a.y,
                                acc[2]*inv + b4a.z, acc[3]*inv + b4a.w);
        float4 o2 = make_float4(acc[4]*inv + b4b.x, acc[5]*inv + b4b.y,
                                acc[6]*inv + b4b.z, acc[7]*inv + b4b.w);
        ((float4*)out)[(size_t)d*16 + c8*2    ] = o1;
        ((float4*)out)[(size_t)d*16 + c8*2 + 1] = o2;
    }
}

// ---------------- virtual-node stage ----------------
__global__ __launch_bounds__(256) void k_vn_segsum2(const float* __restrict__ outA,
                                                    const int* __restrict__ nodes,
                                                    const int* __restrict__ binptr,
                                                    float* __restrict__ vseg){   // [256*NSLICE][64]
    __shared__ float part[4][64];
    int b = blockIdx.x >> 3, s = blockIdx.x & (NSLICE-1);
    int wv = threadIdx.x >> 6, lane = threadIdx.x & 63;
    int i0 = binptr[b], i1 = binptr[b+1];
    int len = i1 - i0;
    int lo = i0 + (len*s)/NSLICE;
    int hi = i0 + (len*(s+1))/NSLICE;
    float acc = 0.f;
    for (int i = lo + wv; i < hi; i += 4){
        int n = nodes[i];
        acc += outA[(size_t)n*64 + lane];
    }
    part[wv][lane] = acc;
    __syncthreads();
    if (threadIdx.x < 64)
        vseg[(size_t)blockIdx.x*64 + lane] =
            part[0][lane] + part[1][lane] + part[2][lane] + part[3][lane];
}

__global__ __launch_bounds__(256) void k_vn_combine(const float* __restrict__ vseg,
                                                    const float* __restrict__ vd_old,
                                                    const float* __restrict__ root_old,
                                                    const float* __restrict__ vn_emb,
                                                    float* __restrict__ vw){   // [257][64]
    __shared__ float part[4][64];
    int wv = threadIdx.x >> 6, lane = threadIdx.x & 63;
    float rold = root_old ? root_old[lane] : vn_emb[lane];
    float emb  = vn_emb[lane];
    float csum = 0.f;
    for (int b = wv*64; b < wv*64 + 64; ++b){
        float v = 0.f;
        #pragma unroll
        for (int s = 0; s < NSLICE; ++s)
            v += vseg[(size_t)(b*NSLICE + s)*64 + lane];
        v += (vd_old ? vd_old[b*64 + lane] : emb) + rold;
        vw[b*64 + lane] = v;
        csum += v;
    }
    part[wv][lane] = csum;
    __syncthreads();
    if (threadIdx.x < 64)
        vw[256*64 + lane] = part[0][lane] + part[1][lane] + part[2][lane] + part[3][lane] + rold;
}

__global__ __launch_bounds__(256) void k_vn_mlp(const float* __restrict__ mlp_w1,
                                                const float* __restrict__ mlp_b1,
                                                const float* __restrict__ mlp_w2,
                                                const float* __restrict__ mlp_b2,
                                                int L, float* __restrict__ vw){
    __shared__ float Wl[64*64];
    int wv = blockIdx.x*4 + (threadIdx.x >> 6);
    int lane = threadIdx.x & 63;
    bool valid = (wv < 257);
    float iv = valid ? vw[wv*64 + lane] : 0.f;
    for (int m = 0; m < L; ++m){
        #pragma unroll
        for (int half = 0; half < 2; ++half){
            const float* W    = (half ? mlp_w2 : mlp_w1) + (size_t)m*4096;
            const float* bias = (half ? mlp_b2 : mlp_b1) + (size_t)m*64;
            __syncthreads();
            for (int i = threadIdx.x; i < 4096; i += 256) Wl[i] = W[i];
            __syncthreads();
            float acc = bias[lane];
            #pragma unroll
            for (int k = 0; k < 64; ++k)
                acc += __shfl(iv, k, 64) * Wl[k*64 + lane];
            iv = fmaxf(acc, 0.f);
        }
    }
    if (valid) vw[wv*64 + lane] = iv;
}

extern "C" void kernel_launch(void* const* d_in, const int* in_sizes, int n_in,
                              void* d_out, int out_size, void* d_ws, size_t ws_size,
                              hipStream_t stream) {
    const int N = in_sizes[0] / 3;
    const int E = in_sizes[1] / 2;
    const int L = in_sizes[9] / (64*64);
    const int NB = (N + (1<<BSHIFT) - 1) >> BSHIFT;

    const float* x        = (const float*)d_in[0];
    const int*   edge     = (const int*)d_in[1];
    const int*   srcp     = edge;
    const int*   dstp     = edge + E;
    const int*   hb       = (const int*)d_in[2];
    const float* w_in     = (const float*)d_in[5];
    const float* a_src_in = (const float*)d_in[6];
    const float* a_dst_in = (const float*)d_in[7];
    const float* b_in     = (const float*)d_in[8];
    const float* w_l      = (const float*)d_in[9];
    const float* a_src_l  = (const float*)d_in[10];
    const float* a_dst_l  = (const float*)d_in[11];
    const float* b_l      = (const float*)d_in[12];
    const float* mlp_w1   = (const float*)d_in[13];
    const float* mlp_b1   = (const float*)d_in[14];
    const float* mlp_w2   = (const float*)d_in[15];
    const float* mlp_b2   = (const float*)d_in[16];
    const float* vn_emb   = (const float*)d_in[17];
    float*       out      = (float*)d_out;

    // ---- workspace carve (256B-aligned) ----
    char* ws = (char*)d_ws;
    size_t off = 0;
    auto carve = [&](size_t bytes) -> char* {
        char* p = ws + off;
        off = (off + bytes + 255) & ~(size_t)255;
        return p;
    };
    unsigned short* h = (unsigned short*)carve((size_t)N*64*2);  // aliased as pairs in CSR build
    float* outA   = (float*)carve((size_t)N*64*4);
    float* ssrc   = (float*)carve((size_t)N*4);
    float* sdst   = (float*)carve((size_t)N*4);
    int*   rowptr = (int*)carve((size_t)(N+1)*4);
    char*  zstart = ws + off;
    int*   bucketCount = (int*)carve(256*4);
    int*   hbBins = (int*)carve(256*4);
    size_t zbytes = (size_t)((ws + off) - zstart);
    int*   bucketOff = (int*)carve(257*4);
    int*   bucketCur = (int*)carve(256*4);
    int*   binptr = (int*)carve(257*4);
    int*   bincur = (int*)carve(256*4);
    int*   colarr = (int*)carve((size_t)E*4);
    int*   nodes  = (int*)carve((size_t)N*4);
    float* vseg   = (float*)carve((size_t)256*NSLICE*64*4);
    float* vw     = (float*)carve((size_t)257*64*4);
    if (off > ws_size) return;
    int2* pairs = (int2*)h;   // E*8 <= N*128 bytes; pairs dead before h's first write

    // ---- CSR + node-bin build ----
    hipMemsetAsync(zstart, 0, zbytes, stream);
    const int nchunkE = (E + CHUNK - 1) / CHUNK;
    const int nchunkN = (N + CHUNK - 1) / CHUNK;
    k_count       <<<nchunkE, 256, 0, stream>>>(dstp, E, NB, bucketCount, hb, N, hbBins);
    k_scan_all    <<<1, 256, 0, stream>>>(bucketCount, NB, E, N, bucketOff, bucketCur, rowptr,
                                          hbBins, binptr, bincur);
    k_bucket_place<<<nchunkE, 256, 0, stream>>>(srcp, dstp, E, NB, bucketCur, pairs);
    k_bucket_csr  <<<NB, 256, 0, stream>>>(pairs, bucketOff, N, rowptr, colarr);
    k_hb_place    <<<nchunkN, 256, 0, stream>>>(hb, N, bincur, nodes);

    const int nwb = (N + 3) / 4;     // wave-per-node kernels
    const int nab = (N + 7) / 8;     // aggregate: 2 dst/wave, 8 dst/block
    const int nmb = (N + 63) / 64;   // mfma transform blocks

    // ---- GAT layer 0 (IN -> H) ----
    k_transform_in<<<nwb, 256, 0, stream>>>(x, w_in, a_src_in, a_dst_in, h, ssrc, sdst, N);
    k_aggregate<<<nab, 256, 0, stream>>>(h, ssrc, sdst, rowptr, colarr, b_in, outA, N);

    // ---- hidden layers ----
    for (int l = 0; l < L; ++l){
        const float* vnp = (l == 0) ? nullptr : vw;
        k_transform_h_mfma<<<nmb, 256, 0, stream>>>(outA, vnp, vn_emb, hb,
                                                    w_l + (size_t)l*4096,
                                                    a_src_l + (size_t)l*64,
                                                    a_dst_l + (size_t)l*64,
                                                    h, ssrc, sdst, N);
        const bool last = (l == L-1);
        float* dst_buf = last ? out : outA;
        k_aggregate<<<nab, 256, 0, stream>>>(h, ssrc, sdst, rowptr, colarr,
                                             b_l + (size_t)l*64, dst_buf, N);
        if (!last){
            const float* vdo = (l == 0) ? nullptr : vw;
            const float* ro  = (l == 0) ? nullptr : (vw + 256*64);
            k_vn_segsum2<<<256*NSLICE, 256, 0, stream>>>(outA, nodes, binptr, vseg);
            k_vn_combine<<<1, 256, 0, stream>>>(vseg, vdo, ro, vn_emb, vw);
            k_vn_mlp<<<(257+3)/4, 256, 0, stream>>>(mlp_w1, mlp_b1, mlp_w2, mlp_b2, L, vw);
        }
    }
}

// Round 11
// 352.369 us; speedup vs baseline: 1.2423x; 1.0224x over previous
//
#include <hip/hip_runtime.h>

// GNN with hierarchical virtual nodes. FP32 in/out, int32 indices.
//
//  CSR build: bucketed (dst>>9) two-level sort -> per-bucket-owned colarr.
//  Node list grouped by hb (counting sort) for the VN segment-sum.
//  h stored BF16 128B rows (64B-line aligned); ssrc/sdst separate fp32 arrays
//  (L2-resident; R8 showed embedding them in the row breaks alignment, +50MB).
//  Aggregate: FOUR dst per wave (16 lanes each; chunk=16 fits Poisson(12)
//  degree), phase-B 8 lanes/row uint4 gathers unrolled x4 (8 rows in flight).
//  Softmax referenced to self-loop alpha (shift-invariant).
//  (VN update after the last layer never reaches the output -> skipped)

typedef __attribute__((ext_vector_type(8))) short short8;
typedef __attribute__((ext_vector_type(4))) float f32x4;

__device__ __forceinline__ unsigned short f2bf(float x){      // RNE float->bf16
    unsigned u = __float_as_uint(x);
    unsigned r = (u + 0x7fffu + ((u >> 16) & 1u)) >> 16;
    return (unsigned short)r;
}
__device__ __forceinline__ float bf2f(unsigned short b){
    return __uint_as_float(((unsigned)b) << 16);
}

#define BSHIFT 9
#define CHUNK 4096
#define NSLICE 8

// inclusive scan of v across the 256 threads of the block (4 waves)
__device__ __forceinline__ int incl_scan256(int v, int* sums4){
    int lane = threadIdx.x & 63, w = threadIdx.x >> 6;
    int x = v;
    #pragma unroll
    for (int o = 1; o < 64; o <<= 1){ int t = __shfl_up(x, o, 64); if (lane >= o) x += t; }
    __syncthreads();
    if (lane == 63) sums4[w] = x;
    __syncthreads();
    for (int j = 0; j < w; ++j) x += sums4[j];
    return x;
}

// ---------------- bucketed CSR build ----------------
__global__ __launch_bounds__(256) void k_count(const int* __restrict__ dst, int E, int NB,
                                               int* __restrict__ bucketCount,
                                               const int* __restrict__ hb, int N,
                                               int* __restrict__ hbBins){
    __shared__ int cnt[256], cnt2[256];
    cnt[threadIdx.x] = 0; cnt2[threadIdx.x] = 0;
    __syncthreads();
    int base = blockIdx.x*CHUNK;
    int lim = min(base + CHUNK, E);
    for (int i = base + threadIdx.x; i < lim; i += 256)
        atomicAdd(&cnt[dst[i] >> BSHIFT], 1);
    int limN = min(base + CHUNK, N);
    for (int i = base + threadIdx.x; i < limN; i += 256)
        atomicAdd(&cnt2[hb[i]], 1);
    __syncthreads();
    if (threadIdx.x < NB && cnt[threadIdx.x])
        atomicAdd(&bucketCount[threadIdx.x], cnt[threadIdx.x]);
    if (cnt2[threadIdx.x])
        atomicAdd(&hbBins[threadIdx.x], cnt2[threadIdx.x]);
}

__global__ __launch_bounds__(256) void k_scan_all(const int* __restrict__ bucketCount,
                                                  int NB, int E, int N,
                                                  int* __restrict__ bucketOff,
                                                  int* __restrict__ bucketCur,
                                                  int* __restrict__ rowptr,
                                                  const int* __restrict__ hbBins,
                                                  int* __restrict__ binptr,
                                                  int* __restrict__ bincur){
    __shared__ int sums4[4];
    int tid = threadIdx.x;
    int v = (tid < NB) ? bucketCount[tid] : 0;
    int x = incl_scan256(v, sums4);
    if (tid < NB){ bucketOff[tid] = x - v; bucketCur[tid] = x - v; }
    if (tid == NB-1) bucketOff[NB] = x;
    if (tid == 0) rowptr[N] = E;
    int v2 = hbBins[tid];
    int x2 = incl_scan256(v2, sums4);
    binptr[tid] = x2 - v2;
    bincur[tid] = x2 - v2;
    if (tid == 255) binptr[256] = x2;
}

__global__ __launch_bounds__(256) void k_bucket_place(const int* __restrict__ src,
                                                      const int* __restrict__ dst, int E, int NB,
                                                      int* __restrict__ bucketCur,
                                                      int2* __restrict__ pairs){
    __shared__ int cnt[256], binStart[256], binCur[256], chunkBase[256];
    __shared__ int sums4[4];
    __shared__ int2 lp[CHUNK];
    int tid = threadIdx.x;
    cnt[tid] = 0; binCur[tid] = 0;
    __syncthreads();
    int base = blockIdx.x*CHUNK;
    int s[16], d[16];
    #pragma unroll
    for (int k = 0; k < 16; ++k){
        int i = base + k*256 + tid;
        if (i < E){ s[k] = src[i]; d[k] = dst[i]; atomicAdd(&cnt[d[k] >> BSHIFT], 1); }
        else d[k] = -1;
    }
    __syncthreads();
    int v = cnt[tid];
    int x = incl_scan256(v, sums4);
    binStart[tid] = x - v;
    __syncthreads();
    #pragma unroll
    for (int k = 0; k < 16; ++k){
        if (d[k] >= 0){
            int b = d[k] >> BSHIFT;
            int p = binStart[b] + atomicAdd(&binCur[b], 1);
            lp[p] = make_int2(s[k], d[k]);
        }
    }
    if (tid < NB){
        int c = cnt[tid];
        chunkBase[tid] = c ? atomicAdd(&bucketCur[tid], c) : 0;
    }
    __syncthreads();
    int total = min(CHUNK, E - base);
    for (int i = tid; i < total; i += 256){
        int2 p = lp[i];
        int b = p.y >> BSHIFT;
        pairs[chunkBase[b] + (i - binStart[b])] = p;
    }
}

__global__ __launch_bounds__(256) void k_hb_place(const int* __restrict__ hb, int N,
                                                  int* __restrict__ bincur,
                                                  int* __restrict__ nodes){
    __shared__ int cnt[256], binStart[256], binCur[256], chunkBase[256];
    __shared__ int sums4[4];
    __shared__ int lp[CHUNK];
    __shared__ unsigned char lb[CHUNK];
    int tid = threadIdx.x;
    cnt[tid] = 0; binCur[tid] = 0;
    __syncthreads();
    int base = blockIdx.x*CHUNK;
    int key[16];
    #pragma unroll
    for (int k = 0; k < 16; ++k){
        int i = base + k*256 + tid;
        key[k] = (i < N) ? hb[i] : -1;
        if (key[k] >= 0) atomicAdd(&cnt[key[k]], 1);
    }
    __syncthreads();
    int v = cnt[tid];
    int x = incl_scan256(v, sums4);
    binStart[tid] = x - v;
    __syncthreads();
    #pragma unroll
    for (int k = 0; k < 16; ++k){
        if (key[k] >= 0){
            int p = binStart[key[k]] + atomicAdd(&binCur[key[k]], 1);
            lp[p] = base + k*256 + tid;
            lb[p] = (unsigned char)key[k];
        }
    }
    if (cnt[tid]) chunkBase[tid] = atomicAdd(&bincur[tid], cnt[tid]);
    __syncthreads();
    int total = min(CHUNK, N - base);
    for (int i = tid; i < total; i += 256){
        int b = lb[i];
        nodes[chunkBase[b] + (i - binStart[b])] = lp[i];
    }
}

__global__ __launch_bounds__(256) void k_bucket_csr(const int2* __restrict__ pairs,
                                                    const int* __restrict__ bucketOff, int N,
                                                    int* __restrict__ rowptr,
                                                    int* __restrict__ colarr){
    __shared__ int deg[512], cur[512];
    __shared__ int sums4[4];
    __shared__ int tAs;
    int b = blockIdx.x, tid = threadIdx.x;
    int d0 = b << BSHIFT;
    int e0 = bucketOff[b], e1 = bucketOff[b+1];
    deg[tid] = 0; deg[256+tid] = 0;
    __syncthreads();
    for (int i = e0 + tid; i < e1; i += 256)
        atomicAdd(&deg[pairs[i].y - d0], 1);
    __syncthreads();
    int vA = deg[tid], vB = deg[256+tid];
    int xA = incl_scan256(vA, sums4);
    if (tid == 255) tAs = xA;
    int xB = incl_scan256(vB, sums4) + tAs;
    int exclA = xA - vA, exclB = xB - vB;
    cur[tid] = exclA; cur[256+tid] = exclB;
    int dA = d0 + tid, dB = d0 + 256 + tid;
    if (dA < N) rowptr[dA] = e0 + exclA;
    if (dB < N) rowptr[dB] = e0 + exclB;
    __syncthreads();
    for (int i = e0 + tid; i < e1; i += 256){
        int2 p = pairs[i];
        int pos = e0 + atomicAdd(&cur[p.y - d0], 1);
        colarr[pos] = p.x;
    }
}

// ---------------- transforms ----------------
__global__ __launch_bounds__(256) void k_transform_in(const float* __restrict__ x,
                                                      const float* __restrict__ W,  // [3][64]
                                                      const float* __restrict__ a_src,
                                                      const float* __restrict__ a_dst,
                                                      unsigned short* __restrict__ hout,  // bf16 64/row
                                                      float* __restrict__ ssrc,
                                                      float* __restrict__ sdst, int N){
    int wv = blockIdx.x*4 + (threadIdx.x >> 6);
    int lane = threadIdx.x & 63;
    if (wv >= N) return;
    float acc = 0.f;
    #pragma unroll
    for (int k = 0; k < 3; ++k)
        acc += x[wv*3 + k] * W[k*64 + lane];
    hout[(size_t)wv*64 + lane] = f2bf(acc);
    float v1 = acc * a_src[lane];
    float v2 = acc * a_dst[lane];
    #pragma unroll
    for (int o = 32; o; o >>= 1){ v1 += __shfl_xor(v1, o, 64); v2 += __shfl_xor(v2, o, 64); }
    if (lane == 0){ ssrc[wv] = v1; sdst[wv] = v2; }
}

// MFMA transform: 64 rows/block; split-bf16 X@W ~= Xh@Wh + Xh@Wl + Xl@Wh.
#define LDW 72
__global__ __launch_bounds__(256) void k_transform_h_mfma(const float* __restrict__ feat,
                                                          const float* __restrict__ vn,      // [256][64] or null
                                                          const float* __restrict__ vn_emb,  // used if vn null
                                                          const int* __restrict__ hb,
                                                          const float* __restrict__ W,       // [64][64]
                                                          const float* __restrict__ a_src,
                                                          const float* __restrict__ a_dst,
                                                          unsigned short* __restrict__ hout, // bf16 64/row
                                                          float* __restrict__ ssrc,
                                                          float* __restrict__ sdst, int N){
    __shared__ unsigned short WhT[64*LDW], WlT[64*LDW], Ah[64*LDW], Al[64*LDW];
    const int n0 = blockIdx.x * 64;

    for (int idx = threadIdx.x; idx < 4096; idx += 256){
        int n = idx >> 6, k = idx & 63;
        float w = W[k*64 + n];
        unsigned short hi = f2bf(w);
        WhT[n*LDW + k] = hi;
        WlT[n*LDW + k] = f2bf(w - bf2f(hi));
    }
    for (int t = threadIdx.x; t < 1024; t += 256){
        int row = t >> 4, c4 = t & 15;
        int node = n0 + row;
        float4 v = make_float4(0.f,0.f,0.f,0.f);
        if (node < N){
            v = ((const float4*)feat)[(size_t)node*16 + c4];
            float4 g = vn ? ((const float4*)vn)[(size_t)hb[node]*16 + c4]
                          : ((const float4*)vn_emb)[c4];
            v.x += g.x; v.y += g.y; v.z += g.z; v.w += g.w;
        }
        int base = row*LDW + c4*4;
        unsigned short h0 = f2bf(v.x), h1 = f2bf(v.y), h2 = f2bf(v.z), h3 = f2bf(v.w);
        Ah[base+0] = h0; Al[base+0] = f2bf(v.x - bf2f(h0));
        Ah[base+1] = h1; Al[base+1] = f2bf(v.y - bf2f(h1));
        Ah[base+2] = h2; Al[base+2] = f2bf(v.z - bf2f(h2));
        Ah[base+3] = h3; Al[base+3] = f2bf(v.w - bf2f(h3));
    }
    __syncthreads();

    int lane = threadIdx.x & 63;
    int wv   = threadIdx.x >> 6;
    int mrow = lane & 15, quad = lane >> 4;
    int m0 = wv * 16;

    f32x4 acc0 = {0,0,0,0}, acc1 = {0,0,0,0}, acc2 = {0,0,0,0}, acc3 = {0,0,0,0};
    #pragma unroll
    for (int k0 = 0; k0 < 64; k0 += 32){
        int kb = k0 + quad*8;
        short8 ah = *(const short8*)&Ah[(m0+mrow)*LDW + kb];
        short8 al = *(const short8*)&Al[(m0+mrow)*LDW + kb];
        short8 b0h = *(const short8*)&WhT[( 0+mrow)*LDW + kb];
        short8 b1h = *(const short8*)&WhT[(16+mrow)*LDW + kb];
        short8 b2h = *(const short8*)&WhT[(32+mrow)*LDW + kb];
        short8 b3h = *(const short8*)&WhT[(48+mrow)*LDW + kb];
        short8 b0l = *(const short8*)&WlT[( 0+mrow)*LDW + kb];
        short8 b1l = *(const short8*)&WlT[(16+mrow)*LDW + kb];
        short8 b2l = *(const short8*)&WlT[(32+mrow)*LDW + kb];
        short8 b3l = *(const short8*)&WlT[(48+mrow)*LDW + kb];
        acc0 = __builtin_amdgcn_mfma_f32_16x16x32_bf16(ah, b0h, acc0, 0, 0, 0);
        acc1 = __builtin_amdgcn_mfma_f32_16x16x32_bf16(ah, b1h, acc1, 0, 0, 0);
        acc2 = __builtin_amdgcn_mfma_f32_16x16x32_bf16(ah, b2h, acc2, 0, 0, 0);
        acc3 = __builtin_amdgcn_mfma_f32_16x16x32_bf16(ah, b3h, acc3, 0, 0, 0);
        acc0 = __builtin_amdgcn_mfma_f32_16x16x32_bf16(ah, b0l, acc0, 0, 0, 0);
        acc1 = __builtin_amdgcn_mfma_f32_16x16x32_bf16(ah, b1l, acc1, 0, 0, 0);
        acc2 = __builtin_amdgcn_mfma_f32_16x16x32_bf16(ah, b2l, acc2, 0, 0, 0);
        acc3 = __builtin_amdgcn_mfma_f32_16x16x32_bf16(ah, b3l, acc3, 0, 0, 0);
        acc0 = __builtin_amdgcn_mfma_f32_16x16x32_bf16(al, b0h, acc0, 0, 0, 0);
        acc1 = __builtin_amdgcn_mfma_f32_16x16x32_bf16(al, b1h, acc1, 0, 0, 0);
        acc2 = __builtin_amdgcn_mfma_f32_16x16x32_bf16(al, b2h, acc2, 0, 0, 0);
        acc3 = __builtin_amdgcn_mfma_f32_16x16x32_bf16(al, b3h, acc3, 0, 0, 0);
    }

    float as0 = a_src[mrow], as1 = a_src[16+mrow], as2 = a_src[32+mrow], as3 = a_src[48+mrow];
    float ad0 = a_dst[mrow], ad1 = a_dst[16+mrow], ad2 = a_dst[32+mrow], ad3 = a_dst[48+mrow];
    #pragma unroll
    for (int r = 0; r < 4; ++r){
        float p1 = acc0[r]*as0 + acc1[r]*as1 + acc2[r]*as2 + acc3[r]*as3;
        float p2 = acc0[r]*ad0 + acc1[r]*ad1 + acc2[r]*ad2 + acc3[r]*ad3;
        #pragma unroll
        for (int o = 8; o; o >>= 1){ p1 += __shfl_xor(p1, o, 64); p2 += __shfl_xor(p2, o, 64); }
        int node = n0 + m0 + quad*4 + r;
        if (mrow == 0 && node < N){ ssrc[node] = p1; sdst[node] = p2; }
    }
    // restage C as bf16 into this wave's own Ah rows, then coalesced row stores
    #pragma unroll
    for (int r = 0; r < 4; ++r){
        int row = m0 + quad*4 + r;
        Ah[row*LDW + mrow     ] = f2bf(acc0[r]);
        Ah[row*LDW + mrow + 16] = f2bf(acc1[r]);
        Ah[row*LDW + mrow + 32] = f2bf(acc2[r]);
        Ah[row*LDW + mrow + 48] = f2bf(acc3[r]);
    }
    int r2 = lane >> 2, seg = lane & 3;
    int node = n0 + m0 + r2;
    if (node < N){
        short8 va = *(const short8*)&Ah[(m0+r2)*LDW + seg*16];
        short8 vb = *(const short8*)&Ah[(m0+r2)*LDW + seg*16 + 8];
        *(short8*)&hout[(size_t)node*64 + seg*16]     = va;
        *(short8*)&hout[(size_t)node*64 + seg*16 + 8] = vb;
    }
}

// ---------------- GAT aggregation ----------------
// FOUR dst per wave (16 lanes each; chunk=16). Softmax vs self-loop alpha.
// Phase B: 8 lanes/row, uint4/lane, unrolled x4 -> up to 8 rows in flight.
// All swb indices stay inside the group's 16 slots (always written, w=0 pad).
__global__ __launch_bounds__(256) void k_aggregate(const unsigned short* __restrict__ h,
                                                   const float* __restrict__ ssrc,
                                                   const float* __restrict__ sdst,
                                                   const int* __restrict__ rowptr,
                                                   const int* __restrict__ col,
                                                   const float* __restrict__ bias,
                                                   float* __restrict__ out, int N){
    __shared__ float2 swb[4][64];
    int wv = threadIdx.x >> 6;
    int lane = threadIdx.x & 63;
    int grp = lane >> 4, lane16 = lane & 15;
    int d = blockIdx.x*16 + wv*4 + grp;
    if (d >= N) return;
    int r2 = lane16 >> 3, c8 = lane16 & 7;
    float sd = sdst[d];
    float a0 = ssrc[d] + sd; a0 = (a0 < 0.f) ? 0.2f*a0 : a0;   // self-loop reference
    float dlocal = 0.f;
    float acc[8] = {0,0,0,0,0,0,0,0};
    if (r2 == 0){                                              // self loop, weight 1
        uint4 u = *(const uint4*)&h[(size_t)d*64 + c8*8];
        acc[0] = __uint_as_float(u.x << 16); acc[1] = __uint_as_float(u.x & 0xffff0000u);
        acc[2] = __uint_as_float(u.y << 16); acc[3] = __uint_as_float(u.y & 0xffff0000u);
        acc[4] = __uint_as_float(u.z << 16); acc[5] = __uint_as_float(u.z & 0xffff0000u);
        acc[6] = __uint_as_float(u.w << 16); acc[7] = __uint_as_float(u.w & 0xffff0000u);
    }
    int e0 = rowptr[d], e1 = rowptr[d+1];
    for (int base = e0; base < e1; base += 16){
        int ne = min(16, e1 - base);
        float w = 0.f; int s = 0;
        if (lane16 < ne){
            s = col[base + lane16];
            float a = ssrc[s] + sd;                            // L2-resident gather
            a = (a < 0.f) ? 0.2f*a : a;
            w = __expf(a - a0);
        }
        dlocal += w;
        swb[wv][lane] = make_float2(w, __int_as_float(s));     // pad slots: w=0,s=0
        int nj = (ne + 1) >> 1;                                // steps of 2 rows
        for (int j = 0; j < nj; j += 4){                       // x4 unroll: 8 rows in flight
            // max slot index = (j+3)*2 + r2 <= 15 since nj <= 8 -> in-group, safe
            float2 p0 = swb[wv][grp*16 + (j+0)*2 + r2];
            float2 p1 = swb[wv][grp*16 + (j+1)*2 + r2];
            float2 p2 = swb[wv][grp*16 + (j+2)*2 + r2];
            float2 p3 = swb[wv][grp*16 + (j+3)*2 + r2];
            int s0 = __float_as_int(p0.y), s1 = __float_as_int(p1.y);
            int s2 = __float_as_int(p2.y), s3 = __float_as_int(p3.y);
            uint4 u0 = *(const uint4*)&h[(size_t)s0*64 + c8*8];
            uint4 u1 = *(const uint4*)&h[(size_t)s1*64 + c8*8];
            uint4 u2 = *(const uint4*)&h[(size_t)s2*64 + c8*8];
            uint4 u3 = *(const uint4*)&h[(size_t)s3*64 + c8*8];
            acc[0] += p0.x * __uint_as_float(u0.x << 16);
            acc[1] += p0.x * __uint_as_float(u0.x & 0xffff0000u);
            acc[2] += p0.x * __uint_as_float(u0.y << 16);
            acc[3] += p0.x * __uint_as_float(u0.y & 0xffff0000u);
            acc[4] += p0.x * __uint_as_float(u0.z << 16);
            acc[5] += p0.x * __uint_as_float(u0.z & 0xffff0000u);
            acc[6] += p0.x * __uint_as_float(u0.w << 16);
            acc[7] += p0.x * __uint_as_float(u0.w & 0xffff0000u);
            acc[0] += p1.x * __uint_as_float(u1.x << 16);
            acc[1] += p1.x * __uint_as_float(u1.x & 0xffff0000u);
            acc[2] += p1.x * __uint_as_float(u1.y << 16);
            acc[3] += p1.x * __uint_as_float(u1.y & 0xffff0000u);
            acc[4] += p1.x * __uint_as_float(u1.z << 16);
            acc[5] += p1.x * __uint_as_float(u1.z & 0xffff0000u);
            acc[6] += p1.x * __uint_as_float(u1.w << 16);
            acc[7] += p1.x * __uint_as_float(u1.w & 0xffff0000u);
            acc[0] += p2.x * __uint_as_float(u2.x << 16);
            acc[1] += p2.x * __uint_as_float(u2.x & 0xffff0000u);
            acc[2] += p2.x * __uint_as_float(u2.y << 16);
            acc[3] += p2.x * __uint_as_float(u2.y & 0xffff0000u);
            acc[4] += p2.x * __uint_as_float(u2.z << 16);
            acc[5] += p2.x * __uint_as_float(u2.z & 0xffff0000u);
            acc[6] += p2.x * __uint_as_float(u2.w << 16);
            acc[7] += p2.x * __uint_as_float(u2.w & 0xffff0000u);
            acc[0] += p3.x * __uint_as_float(u3.x << 16);
            acc[1] += p3.x * __uint_as_float(u3.x & 0xffff0000u);
            acc[2] += p3.x * __uint_as_float(u3.y << 16);
            acc[3] += p3.x * __uint_as_float(u3.y & 0xffff0000u);
            acc[4] += p3.x * __uint_as_float(u3.z << 16);
            acc[5] += p3.x * __uint_as_float(u3.z & 0xffff0000u);
            acc[6] += p3.x * __uint_as_float(u3.w << 16);
            acc[7] += p3.x * __uint_as_float(u3.w & 0xffff0000u);
        }
    }
    // reductions confined to the 16-lane group
    #pragma unroll
    for (int o = 8; o; o >>= 1) dlocal += __shfl_xor(dlocal, o, 64);
    float denom = 1.0f + dlocal;
    #pragma unroll
    for (int k = 0; k < 8; ++k) acc[k] += __shfl_xor(acc[k], 8, 64);
    if (r2 == 0){
        float inv = 1.0f/denom;
        float4 b4a = ((const float4*)bias)[c8*2];
        float4 b4b = ((const float4*)bias)[c8*2 + 1];
        float4 o1 = make_float4(acc[0]*inv + b4a.x, acc[1]*inv + b4a.y,
                                acc[2]*inv + b4a.z, acc[3]*inv + b4a.w);
        float4 o2 = make_float4(acc[4]*inv + b4b.x, acc[5]*inv + b4b.y,
                                acc[6]*inv + b4b.z, acc[7]*inv + b4b.w);
        ((float4*)out)[(size_t)d*16 + c8*2    ] = o1;
        ((float4*)out)[(size_t)d*16 + c8*2 + 1] = o2;
    }
}

// ---------------- virtual-node stage ----------------
__global__ __launch_bounds__(256) void k_vn_segsum2(const float* __restrict__ outA,
                                                    const int* __restrict__ nodes,
                                                    const int* __restrict__ binptr,
                                                    float* __restrict__ vseg){   // [256*NSLICE][64]
    __shared__ float part[4][64];
    int b = blockIdx.x >> 3, s = blockIdx.x & (NSLICE-1);
    int wv = threadIdx.x >> 6, lane = threadIdx.x & 63;
    int i0 = binptr[b], i1 = binptr[b+1];
    int len = i1 - i0;
    int lo = i0 + (len*s)/NSLICE;
    int hi = i0 + (len*(s+1))/NSLICE;
    float acc = 0.f;
    for (int i = lo + wv; i < hi; i += 4){
        int n = nodes[i];
        acc += outA[(size_t)n*64 + lane];
    }
    part[wv][lane] = acc;
    __syncthreads();
    if (threadIdx.x < 64)
        vseg[(size_t)blockIdx.x*64 + lane] =
            part[0][lane] + part[1][lane] + part[2][lane] + part[3][lane];
}

__global__ __launch_bounds__(256) void k_vn_combine(const float* __restrict__ vseg,
                                                    const float* __restrict__ vd_old,
                                                    const float* __restrict__ root_old,
                                                    const float* __restrict__ vn_emb,
                                                    float* __restrict__ vw){   // [257][64]
    __shared__ float part[4][64];
    int wv = threadIdx.x >> 6, lane = threadIdx.x & 63;
    float rold = root_old ? root_old[lane] : vn_emb[lane];
    float emb  = vn_emb[lane];
    float csum = 0.f;
    for (int b = wv*64; b < wv*64 + 64; ++b){
        float v = 0.f;
        #pragma unroll
        for (int s = 0; s < NSLICE; ++s)
            v += vseg[(size_t)(b*NSLICE + s)*64 + lane];
        v += (vd_old ? vd_old[b*64 + lane] : emb) + rold;
        vw[b*64 + lane] = v;
        csum += v;
    }
    part[wv][lane] = csum;
    __syncthreads();
    if (threadIdx.x < 64)
        vw[256*64 + lane] = part[0][lane] + part[1][lane] + part[2][lane] + part[3][lane] + rold;
}

__global__ __launch_bounds__(256) void k_vn_mlp(const float* __restrict__ mlp_w1,
                                                const float* __restrict__ mlp_b1,
                                                const float* __restrict__ mlp_w2,
                                                const float* __restrict__ mlp_b2,
                                                int L, float* __restrict__ vw){
    __shared__ float Wl[64*64];
    int wv = blockIdx.x*4 + (threadIdx.x >> 6);
    int lane = threadIdx.x & 63;
    bool valid = (wv < 257);
    float iv = valid ? vw[wv*64 + lane] : 0.f;
    for (int m = 0; m < L; ++m){
        #pragma unroll
        for (int half = 0; half < 2; ++half){
            const float* W    = (half ? mlp_w2 : mlp_w1) + (size_t)m*4096;
            const float* bias = (half ? mlp_b2 : mlp_b1) + (size_t)m*64;
            __syncthreads();
            for (int i = threadIdx.x; i < 4096; i += 256) Wl[i] = W[i];
            __syncthreads();
            float acc = bias[lane];
            #pragma unroll
            for (int k = 0; k < 64; ++k)
                acc += __shfl(iv, k, 64) * Wl[k*64 + lane];
            iv = fmaxf(acc, 0.f);
        }
    }
    if (valid) vw[wv*64 + lane] = iv;
}

extern "C" void kernel_launch(void* const* d_in, const int* in_sizes, int n_in,
                              void* d_out, int out_size, void* d_ws, size_t ws_size,
                              hipStream_t stream) {
    const int N = in_sizes[0] / 3;
    const int E = in_sizes[1] / 2;
    const int L = in_sizes[9] / (64*64);
    const int NB = (N + (1<<BSHIFT) - 1) >> BSHIFT;

    const float* x        = (const float*)d_in[0];
    const int*   edge     = (const int*)d_in[1];
    const int*   srcp     = edge;
    const int*   dstp     = edge + E;
    const int*   hb       = (const int*)d_in[2];
    const float* w_in     = (const float*)d_in[5];
    const float* a_src_in = (const float*)d_in[6];
    const float* a_dst_in = (const float*)d_in[7];
    const float* b_in     = (const float*)d_in[8];
    const float* w_l      = (const float*)d_in[9];
    const float* a_src_l  = (const float*)d_in[10];
    const float* a_dst_l  = (const float*)d_in[11];
    const float* b_l      = (const float*)d_in[12];
    const float* mlp_w1   = (const float*)d_in[13];
    const float* mlp_b1   = (const float*)d_in[14];
    const float* mlp_w2   = (const float*)d_in[15];
    const float* mlp_b2   = (const float*)d_in[16];
    const float* vn_emb   = (const float*)d_in[17];
    float*       out      = (float*)d_out;

    // ---- workspace carve (256B-aligned) ----
    char* ws = (char*)d_ws;
    size_t off = 0;
    auto carve = [&](size_t bytes) -> char* {
        char* p = ws + off;
        off = (off + bytes + 255) & ~(size_t)255;
        return p;
    };
    unsigned short* h = (unsigned short*)carve((size_t)N*64*2);  // aliased as pairs in CSR build
    float* outA   = (float*)carve((size_t)N*64*4);
    float* ssrc   = (float*)carve((size_t)N*4);
    float* sdst   = (float*)carve((size_t)N*4);
    int*   rowptr = (int*)carve((size_t)(N+1)*4);
    char*  zstart = ws + off;
    int*   bucketCount = (int*)carve(256*4);
    int*   hbBins = (int*)carve(256*4);
    size_t zbytes = (size_t)((ws + off) - zstart);
    int*   bucketOff = (int*)carve(257*4);
    int*   bucketCur = (int*)carve(256*4);
    int*   binptr = (int*)carve(257*4);
    int*   bincur = (int*)carve(256*4);
    int*   colarr = (int*)carve((size_t)E*4);
    int*   nodes  = (int*)carve((size_t)N*4);
    float* vseg   = (float*)carve((size_t)256*NSLICE*64*4);
    float* vw     = (float*)carve((size_t)257*64*4);
    if (off > ws_size) return;
    int2* pairs = (int2*)h;   // E*8 <= N*128 bytes; pairs dead before h's first write

    // ---- CSR + node-bin build ----
    hipMemsetAsync(zstart, 0, zbytes, stream);
    const int nchunkE = (E + CHUNK - 1) / CHUNK;
    const int nchunkN = (N + CHUNK - 1) / CHUNK;
    k_count       <<<nchunkE, 256, 0, stream>>>(dstp, E, NB, bucketCount, hb, N, hbBins);
    k_scan_all    <<<1, 256, 0, stream>>>(bucketCount, NB, E, N, bucketOff, bucketCur, rowptr,
                                          hbBins, binptr, bincur);
    k_bucket_place<<<nchunkE, 256, 0, stream>>>(srcp, dstp, E, NB, bucketCur, pairs);
    k_bucket_csr  <<<NB, 256, 0, stream>>>(pairs, bucketOff, N, rowptr, colarr);
    k_hb_place    <<<nchunkN, 256, 0, stream>>>(hb, N, bincur, nodes);

    const int nwb = (N + 3) / 4;     // wave-per-node kernels
    const int nab = (N + 15) / 16;   // aggregate: 4 dst/wave, 16 dst/block
    const int nmb = (N + 63) / 64;   // mfma transform blocks

    // ---- GAT layer 0 (IN -> H) ----
    k_transform_in<<<nwb, 256, 0, stream>>>(x, w_in, a_src_in, a_dst_in, h, ssrc, sdst, N);
    k_aggregate<<<nab, 256, 0, stream>>>(h, ssrc, sdst, rowptr, colarr, b_in, outA, N);

    // ---- hidden layers ----
    for (int l = 0; l < L; ++l){
        const float* vnp = (l == 0) ? nullptr : vw;
        k_transform_h_mfma<<<nmb, 256, 0, stream>>>(outA, vnp, vn_emb, hb,
                                                    w_l + (size_t)l*4096,
                                                    a_src_l + (size_t)l*64,
                                                    a_dst_l + (size_t)l*64,
                                                    h, ssrc, sdst, N);
        const bool last = (l == L-1);
        float* dst_buf = last ? out : outA;
        k_aggregate<<<nab, 256, 0, stream>>>(h, ssrc, sdst, rowptr, colarr,
                                             b_l + (size_t)l*64, dst_buf, N);
        if (!last){
            const float* vdo = (l == 0) ? nullptr : vw;
            const float* ro  = (l == 0) ? nullptr : (vw + 256*64);
            k_vn_segsum2<<<256*NSLICE, 256, 0, stream>>>(outA, nodes, binptr, vseg);
            k_vn_combine<<<1, 256, 0, stream>>>(vseg, vdo, ro, vn_emb, vw);
            k_vn_mlp<<<(257+3)/4, 256, 0, stream>>>(mlp_w1, mlp_b1, mlp_w2, mlp_b2, L, vw);
        }
    }
}

// Round 12
// 341.535 us; speedup vs baseline: 1.2817x; 1.0317x over previous
//
#include <hip/hip_runtime.h>

// GNN with hierarchical virtual nodes. FP32 in/out, int32 indices.
//
//  CSR build: bucketed (dst>>9) two-level sort -> per-bucket-owned colarr.
//  Node list grouped by hb (counting sort) for the VN segment-sum.
//  h stored BF16 128B rows; ssrc/sdst separate fp32 arrays (L2-resident).
//  Aggregate: FOUR dst per wave (16 lanes each; chunk=16), phase-B fully
//  unrolled: 8 uint4 gathers in flight per lane (pads gather row 0, w=0).
//  Softmax referenced to self-loop alpha (shift-invariant).
//  VN combine parallelized 64 blocks; root assembly folded into vn_mlp.
//  (VN update after the last layer never reaches the output -> skipped)

typedef __attribute__((ext_vector_type(8))) short short8;
typedef __attribute__((ext_vector_type(4))) float f32x4;

__device__ __forceinline__ unsigned short f2bf(float x){      // RNE float->bf16
    unsigned u = __float_as_uint(x);
    unsigned r = (u + 0x7fffu + ((u >> 16) & 1u)) >> 16;
    return (unsigned short)r;
}
__device__ __forceinline__ float bf2f(unsigned short b){
    return __uint_as_float(((unsigned)b) << 16);
}

#define BSHIFT 9
#define CHUNK 4096
#define NSLICE 8

// inclusive scan of v across the 256 threads of the block (4 waves)
__device__ __forceinline__ int incl_scan256(int v, int* sums4){
    int lane = threadIdx.x & 63, w = threadIdx.x >> 6;
    int x = v;
    #pragma unroll
    for (int o = 1; o < 64; o <<= 1){ int t = __shfl_up(x, o, 64); if (lane >= o) x += t; }
    __syncthreads();
    if (lane == 63) sums4[w] = x;
    __syncthreads();
    for (int j = 0; j < w; ++j) x += sums4[j];
    return x;
}

// ---------------- bucketed CSR build ----------------
__global__ __launch_bounds__(256) void k_count(const int* __restrict__ dst, int E, int NB,
                                               int* __restrict__ bucketCount,
                                               const int* __restrict__ hb, int N,
                                               int* __restrict__ hbBins){
    __shared__ int cnt[256], cnt2[256];
    cnt[threadIdx.x] = 0; cnt2[threadIdx.x] = 0;
    __syncthreads();
    int base = blockIdx.x*CHUNK;
    int lim = min(base + CHUNK, E);
    for (int i = base + threadIdx.x; i < lim; i += 256)
        atomicAdd(&cnt[dst[i] >> BSHIFT], 1);
    int limN = min(base + CHUNK, N);
    for (int i = base + threadIdx.x; i < limN; i += 256)
        atomicAdd(&cnt2[hb[i]], 1);
    __syncthreads();
    if (threadIdx.x < NB && cnt[threadIdx.x])
        atomicAdd(&bucketCount[threadIdx.x], cnt[threadIdx.x]);
    if (cnt2[threadIdx.x])
        atomicAdd(&hbBins[threadIdx.x], cnt2[threadIdx.x]);
}

__global__ __launch_bounds__(256) void k_scan_all(const int* __restrict__ bucketCount,
                                                  int NB, int E, int N,
                                                  int* __restrict__ bucketOff,
                                                  int* __restrict__ bucketCur,
                                                  int* __restrict__ rowptr,
                                                  const int* __restrict__ hbBins,
                                                  int* __restrict__ binptr,
                                                  int* __restrict__ bincur){
    __shared__ int sums4[4];
    int tid = threadIdx.x;
    int v = (tid < NB) ? bucketCount[tid] : 0;
    int x = incl_scan256(v, sums4);
    if (tid < NB){ bucketOff[tid] = x - v; bucketCur[tid] = x - v; }
    if (tid == NB-1) bucketOff[NB] = x;
    if (tid == 0) rowptr[N] = E;
    int v2 = hbBins[tid];
    int x2 = incl_scan256(v2, sums4);
    binptr[tid] = x2 - v2;
    bincur[tid] = x2 - v2;
    if (tid == 255) binptr[256] = x2;
}

__global__ __launch_bounds__(256) void k_bucket_place(const int* __restrict__ src,
                                                      const int* __restrict__ dst, int E, int NB,
                                                      int* __restrict__ bucketCur,
                                                      int2* __restrict__ pairs){
    __shared__ int cnt[256], binStart[256], binCur[256], chunkBase[256];
    __shared__ int sums4[4];
    __shared__ int2 lp[CHUNK];
    int tid = threadIdx.x;
    cnt[tid] = 0; binCur[tid] = 0;
    __syncthreads();
    int base = blockIdx.x*CHUNK;
    int s[16], d[16];
    #pragma unroll
    for (int k = 0; k < 16; ++k){
        int i = base + k*256 + tid;
        if (i < E){ s[k] = src[i]; d[k] = dst[i]; atomicAdd(&cnt[d[k] >> BSHIFT], 1); }
        else d[k] = -1;
    }
    __syncthreads();
    int v = cnt[tid];
    int x = incl_scan256(v, sums4);
    binStart[tid] = x - v;
    __syncthreads();
    #pragma unroll
    for (int k = 0; k < 16; ++k){
        if (d[k] >= 0){
            int b = d[k] >> BSHIFT;
            int p = binStart[b] + atomicAdd(&binCur[b], 1);
            lp[p] = make_int2(s[k], d[k]);
        }
    }
    if (tid < NB){
        int c = cnt[tid];
        chunkBase[tid] = c ? atomicAdd(&bucketCur[tid], c) : 0;
    }
    __syncthreads();
    int total = min(CHUNK, E - base);
    for (int i = tid; i < total; i += 256){
        int2 p = lp[i];
        int b = p.y >> BSHIFT;
        pairs[chunkBase[b] + (i - binStart[b])] = p;
    }
}

__global__ __launch_bounds__(256) void k_hb_place(const int* __restrict__ hb, int N,
                                                  int* __restrict__ bincur,
                                                  int* __restrict__ nodes){
    __shared__ int cnt[256], binStart[256], binCur[256], chunkBase[256];
    __shared__ int sums4[4];
    __shared__ int lp[CHUNK];
    __shared__ unsigned char lb[CHUNK];
    int tid = threadIdx.x;
    cnt[tid] = 0; binCur[tid] = 0;
    __syncthreads();
    int base = blockIdx.x*CHUNK;
    int key[16];
    #pragma unroll
    for (int k = 0; k < 16; ++k){
        int i = base + k*256 + tid;
        key[k] = (i < N) ? hb[i] : -1;
        if (key[k] >= 0) atomicAdd(&cnt[key[k]], 1);
    }
    __syncthreads();
    int v = cnt[tid];
    int x = incl_scan256(v, sums4);
    binStart[tid] = x - v;
    __syncthreads();
    #pragma unroll
    for (int k = 0; k < 16; ++k){
        if (key[k] >= 0){
            int p = binStart[key[k]] + atomicAdd(&binCur[key[k]], 1);
            lp[p] = base + k*256 + tid;
            lb[p] = (unsigned char)key[k];
        }
    }
    if (cnt[tid]) chunkBase[tid] = atomicAdd(&bincur[tid], cnt[tid]);
    __syncthreads();
    int total = min(CHUNK, N - base);
    for (int i = tid; i < total; i += 256){
        int b = lb[i];
        nodes[chunkBase[b] + (i - binStart[b])] = lp[i];
    }
}

__global__ __launch_bounds__(256) void k_bucket_csr(const int2* __restrict__ pairs,
                                                    const int* __restrict__ bucketOff, int N,
                                                    int* __restrict__ rowptr,
                                                    int* __restrict__ colarr){
    __shared__ int deg[512], cur[512];
    __shared__ int sums4[4];
    __shared__ int tAs;
    int b = blockIdx.x, tid = threadIdx.x;
    int d0 = b << BSHIFT;
    int e0 = bucketOff[b], e1 = bucketOff[b+1];
    deg[tid] = 0; deg[256+tid] = 0;
    __syncthreads();
    for (int i = e0 + tid; i < e1; i += 256)
        atomicAdd(&deg[pairs[i].y - d0], 1);
    __syncthreads();
    int vA = deg[tid], vB = deg[256+tid];
    int xA = incl_scan256(vA, sums4);
    if (tid == 255) tAs = xA;
    int xB = incl_scan256(vB, sums4) + tAs;
    int exclA = xA - vA, exclB = xB - vB;
    cur[tid] = exclA; cur[256+tid] = exclB;
    int dA = d0 + tid, dB = d0 + 256 + tid;
    if (dA < N) rowptr[dA] = e0 + exclA;
    if (dB < N) rowptr[dB] = e0 + exclB;
    __syncthreads();
    for (int i = e0 + tid; i < e1; i += 256){
        int2 p = pairs[i];
        int pos = e0 + atomicAdd(&cur[p.y - d0], 1);
        colarr[pos] = p.x;
    }
}

// ---------------- transforms ----------------
__global__ __launch_bounds__(256) void k_transform_in(const float* __restrict__ x,
                                                      const float* __restrict__ W,  // [3][64]
                                                      const float* __restrict__ a_src,
                                                      const float* __restrict__ a_dst,
                                                      unsigned short* __restrict__ hout,  // bf16 64/row
                                                      float* __restrict__ ssrc,
                                                      float* __restrict__ sdst, int N){
    int wv = blockIdx.x*4 + (threadIdx.x >> 6);
    int lane = threadIdx.x & 63;
    if (wv >= N) return;
    float acc = 0.f;
    #pragma unroll
    for (int k = 0; k < 3; ++k)
        acc += x[wv*3 + k] * W[k*64 + lane];
    hout[(size_t)wv*64 + lane] = f2bf(acc);
    float v1 = acc * a_src[lane];
    float v2 = acc * a_dst[lane];
    #pragma unroll
    for (int o = 32; o; o >>= 1){ v1 += __shfl_xor(v1, o, 64); v2 += __shfl_xor(v2, o, 64); }
    if (lane == 0){ ssrc[wv] = v1; sdst[wv] = v2; }
}

// MFMA transform: 64 rows/block; split-bf16 X@W ~= Xh@Wh + Xh@Wl + Xl@Wh.
#define LDW 72
__global__ __launch_bounds__(256) void k_transform_h_mfma(const float* __restrict__ feat,
                                                          const float* __restrict__ vn,      // [256][64] or null
                                                          const float* __restrict__ vn_emb,  // used if vn null
                                                          const int* __restrict__ hb,
                                                          const float* __restrict__ W,       // [64][64]
                                                          const float* __restrict__ a_src,
                                                          const float* __restrict__ a_dst,
                                                          unsigned short* __restrict__ hout, // bf16 64/row
                                                          float* __restrict__ ssrc,
                                                          float* __restrict__ sdst, int N){
    __shared__ unsigned short WhT[64*LDW], WlT[64*LDW], Ah[64*LDW], Al[64*LDW];
    const int n0 = blockIdx.x * 64;

    for (int idx = threadIdx.x; idx < 4096; idx += 256){
        int n = idx >> 6, k = idx & 63;
        float w = W[k*64 + n];
        unsigned short hi = f2bf(w);
        WhT[n*LDW + k] = hi;
        WlT[n*LDW + k] = f2bf(w - bf2f(hi));
    }
    for (int t = threadIdx.x; t < 1024; t += 256){
        int row = t >> 4, c4 = t & 15;
        int node = n0 + row;
        float4 v = make_float4(0.f,0.f,0.f,0.f);
        if (node < N){
            v = ((const float4*)feat)[(size_t)node*16 + c4];
            float4 g = vn ? ((const float4*)vn)[(size_t)hb[node]*16 + c4]
                          : ((const float4*)vn_emb)[c4];
            v.x += g.x; v.y += g.y; v.z += g.z; v.w += g.w;
        }
        int base = row*LDW + c4*4;
        unsigned short h0 = f2bf(v.x), h1 = f2bf(v.y), h2 = f2bf(v.z), h3 = f2bf(v.w);
        Ah[base+0] = h0; Al[base+0] = f2bf(v.x - bf2f(h0));
        Ah[base+1] = h1; Al[base+1] = f2bf(v.y - bf2f(h1));
        Ah[base+2] = h2; Al[base+2] = f2bf(v.z - bf2f(h2));
        Ah[base+3] = h3; Al[base+3] = f2bf(v.w - bf2f(h3));
    }
    __syncthreads();

    int lane = threadIdx.x & 63;
    int wv   = threadIdx.x >> 6;
    int mrow = lane & 15, quad = lane >> 4;
    int m0 = wv * 16;

    f32x4 acc0 = {0,0,0,0}, acc1 = {0,0,0,0}, acc2 = {0,0,0,0}, acc3 = {0,0,0,0};
    #pragma unroll
    for (int k0 = 0; k0 < 64; k0 += 32){
        int kb = k0 + quad*8;
        short8 ah = *(const short8*)&Ah[(m0+mrow)*LDW + kb];
        short8 al = *(const short8*)&Al[(m0+mrow)*LDW + kb];
        short8 b0h = *(const short8*)&WhT[( 0+mrow)*LDW + kb];
        short8 b1h = *(const short8*)&WhT[(16+mrow)*LDW + kb];
        short8 b2h = *(const short8*)&WhT[(32+mrow)*LDW + kb];
        short8 b3h = *(const short8*)&WhT[(48+mrow)*LDW + kb];
        short8 b0l = *(const short8*)&WlT[( 0+mrow)*LDW + kb];
        short8 b1l = *(const short8*)&WlT[(16+mrow)*LDW + kb];
        short8 b2l = *(const short8*)&WlT[(32+mrow)*LDW + kb];
        short8 b3l = *(const short8*)&WlT[(48+mrow)*LDW + kb];
        acc0 = __builtin_amdgcn_mfma_f32_16x16x32_bf16(ah, b0h, acc0, 0, 0, 0);
        acc1 = __builtin_amdgcn_mfma_f32_16x16x32_bf16(ah, b1h, acc1, 0, 0, 0);
        acc2 = __builtin_amdgcn_mfma_f32_16x16x32_bf16(ah, b2h, acc2, 0, 0, 0);
        acc3 = __builtin_amdgcn_mfma_f32_16x16x32_bf16(ah, b3h, acc3, 0, 0, 0);
        acc0 = __builtin_amdgcn_mfma_f32_16x16x32_bf16(ah, b0l, acc0, 0, 0, 0);
        acc1 = __builtin_amdgcn_mfma_f32_16x16x32_bf16(ah, b1l, acc1, 0, 0, 0);
        acc2 = __builtin_amdgcn_mfma_f32_16x16x32_bf16(ah, b2l, acc2, 0, 0, 0);
        acc3 = __builtin_amdgcn_mfma_f32_16x16x32_bf16(ah, b3l, acc3, 0, 0, 0);
        acc0 = __builtin_amdgcn_mfma_f32_16x16x32_bf16(al, b0h, acc0, 0, 0, 0);
        acc1 = __builtin_amdgcn_mfma_f32_16x16x32_bf16(al, b1h, acc1, 0, 0, 0);
        acc2 = __builtin_amdgcn_mfma_f32_16x16x32_bf16(al, b2h, acc2, 0, 0, 0);
        acc3 = __builtin_amdgcn_mfma_f32_16x16x32_bf16(al, b3h, acc3, 0, 0, 0);
    }

    float as0 = a_src[mrow], as1 = a_src[16+mrow], as2 = a_src[32+mrow], as3 = a_src[48+mrow];
    float ad0 = a_dst[mrow], ad1 = a_dst[16+mrow], ad2 = a_dst[32+mrow], ad3 = a_dst[48+mrow];
    #pragma unroll
    for (int r = 0; r < 4; ++r){
        float p1 = acc0[r]*as0 + acc1[r]*as1 + acc2[r]*as2 + acc3[r]*as3;
        float p2 = acc0[r]*ad0 + acc1[r]*ad1 + acc2[r]*ad2 + acc3[r]*ad3;
        #pragma unroll
        for (int o = 8; o; o >>= 1){ p1 += __shfl_xor(p1, o, 64); p2 += __shfl_xor(p2, o, 64); }
        int node = n0 + m0 + quad*4 + r;
        if (mrow == 0 && node < N){ ssrc[node] = p1; sdst[node] = p2; }
    }
    // restage C as bf16 into this wave's own Ah rows, then coalesced row stores
    #pragma unroll
    for (int r = 0; r < 4; ++r){
        int row = m0 + quad*4 + r;
        Ah[row*LDW + mrow     ] = f2bf(acc0[r]);
        Ah[row*LDW + mrow + 16] = f2bf(acc1[r]);
        Ah[row*LDW + mrow + 32] = f2bf(acc2[r]);
        Ah[row*LDW + mrow + 48] = f2bf(acc3[r]);
    }
    int r2 = lane >> 2, seg = lane & 3;
    int node = n0 + m0 + r2;
    if (node < N){
        short8 va = *(const short8*)&Ah[(m0+r2)*LDW + seg*16];
        short8 vb = *(const short8*)&Ah[(m0+r2)*LDW + seg*16 + 8];
        *(short8*)&hout[(size_t)node*64 + seg*16]     = va;
        *(short8*)&hout[(size_t)node*64 + seg*16 + 8] = vb;
    }
}

// ---------------- GAT aggregation ----------------
// FOUR dst per wave (16 lanes each; chunk=16). Softmax vs self-loop alpha.
// Phase B fully unrolled: 8 uint4 gathers issued back-to-back (8 in flight);
// pad slots carry w=0,s=0 -> harmless row-0 gathers (L1-hot).
__global__ __launch_bounds__(256) void k_aggregate(const unsigned short* __restrict__ h,
                                                   const float* __restrict__ ssrc,
                                                   const float* __restrict__ sdst,
                                                   const int* __restrict__ rowptr,
                                                   const int* __restrict__ col,
                                                   const float* __restrict__ bias,
                                                   float* __restrict__ out, int N){
    __shared__ float2 swb[4][64];
    int wv = threadIdx.x >> 6;
    int lane = threadIdx.x & 63;
    int grp = lane >> 4, lane16 = lane & 15;
    int d = blockIdx.x*16 + wv*4 + grp;
    if (d >= N) return;
    int r2 = lane16 >> 3, c8 = lane16 & 7;
    float sd = sdst[d];
    float a0 = ssrc[d] + sd; a0 = (a0 < 0.f) ? 0.2f*a0 : a0;   // self-loop reference
    float dlocal = 0.f;
    float acc[8] = {0,0,0,0,0,0,0,0};
    if (r2 == 0){                                              // self loop, weight 1
        uint4 u = *(const uint4*)&h[(size_t)d*64 + c8*8];
        acc[0] = __uint_as_float(u.x << 16); acc[1] = __uint_as_float(u.x & 0xffff0000u);
        acc[2] = __uint_as_float(u.y << 16); acc[3] = __uint_as_float(u.y & 0xffff0000u);
        acc[4] = __uint_as_float(u.z << 16); acc[5] = __uint_as_float(u.z & 0xffff0000u);
        acc[6] = __uint_as_float(u.w << 16); acc[7] = __uint_as_float(u.w & 0xffff0000u);
    }
    int e0 = rowptr[d], e1 = rowptr[d+1];
    for (int base = e0; base < e1; base += 16){
        int ne = min(16, e1 - base);
        float w = 0.f; int s = 0;
        if (lane16 < ne){
            s = col[base + lane16];
            float a = ssrc[s] + sd;                            // L2-resident gather
            a = (a < 0.f) ? 0.2f*a : a;
            w = __expf(a - a0);
        }
        dlocal += w;
        swb[wv][lane] = make_float2(w, __int_as_float(s));     // pad slots: w=0,s=0
        // fully unrolled: 8 steps x 2 rows, all 16 group slots always written
        float2 p[8];
        #pragma unroll
        for (int j = 0; j < 8; ++j) p[j] = swb[wv][grp*16 + j*2 + r2];
        uint4 u[8];
        #pragma unroll
        for (int j = 0; j < 8; ++j){
            int sj = __float_as_int(p[j].y);
            u[j] = *(const uint4*)&h[(size_t)sj*64 + c8*8];
        }
        #pragma unroll
        for (int j = 0; j < 8; ++j){
            acc[0] += p[j].x * __uint_as_float(u[j].x << 16);
            acc[1] += p[j].x * __uint_as_float(u[j].x & 0xffff0000u);
            acc[2] += p[j].x * __uint_as_float(u[j].y << 16);
            acc[3] += p[j].x * __uint_as_float(u[j].y & 0xffff0000u);
            acc[4] += p[j].x * __uint_as_float(u[j].z << 16);
            acc[5] += p[j].x * __uint_as_float(u[j].z & 0xffff0000u);
            acc[6] += p[j].x * __uint_as_float(u[j].w << 16);
            acc[7] += p[j].x * __uint_as_float(u[j].w & 0xffff0000u);
        }
    }
    // reductions confined to the 16-lane group
    #pragma unroll
    for (int o = 8; o; o >>= 1) dlocal += __shfl_xor(dlocal, o, 64);
    float denom = 1.0f + dlocal;
    #pragma unroll
    for (int k = 0; k < 8; ++k) acc[k] += __shfl_xor(acc[k], 8, 64);
    if (r2 == 0){
        float inv = 1.0f/denom;
        float4 b4a = ((const float4*)bias)[c8*2];
        float4 b4b = ((const float4*)bias)[c8*2 + 1];
        float4 o1 = make_float4(acc[0]*inv + b4a.x, acc[1]*inv + b4a.y,
                                acc[2]*inv + b4a.z, acc[3]*inv + b4a.w);
        float4 o2 = make_float4(acc[4]*inv + b4b.x, acc[5]*inv + b4b.y,
                                acc[6]*inv + b4b.z, acc[7]*inv + b4b.w);
        ((float4*)out)[(size_t)d*16 + c8*2    ] = o1;
        ((float4*)out)[(size_t)d*16 + c8*2 + 1] = o2;
    }
}

// ---------------- virtual-node stage ----------------
__global__ __launch_bounds__(256) void k_vn_segsum2(const float* __restrict__ outA,
                                                    const int* __restrict__ nodes,
                                                    const int* __restrict__ binptr,
                                                    float* __restrict__ vseg){   // [256*NSLICE][64]
    __shared__ float part[4][64];
    int b = blockIdx.x >> 3, s = blockIdx.x & (NSLICE-1);
    int wv = threadIdx.x >> 6, lane = threadIdx.x & 63;
    int i0 = binptr[b], i1 = binptr[b+1];
    int len = i1 - i0;
    int lo = i0 + (len*s)/NSLICE;
    int hi = i0 + (len*(s+1))/NSLICE;
    float acc = 0.f;
    for (int i = lo + wv; i < hi; i += 4){
        int n = nodes[i];
        acc += outA[(size_t)n*64 + lane];
    }
    part[wv][lane] = acc;
    __syncthreads();
    if (threadIdx.x < 64)
        vseg[(size_t)blockIdx.x*64 + lane] =
            part[0][lane] + part[1][lane] + part[2][lane] + part[3][lane];
}

// 64 blocks x 4 rows: vn_direct = segsum + old + root_old; colsum via atomics
__global__ __launch_bounds__(256) void k_vn_combine(const float* __restrict__ vseg,
                                                    const float* __restrict__ vd_old,
                                                    const float* __restrict__ root_old,
                                                    const float* __restrict__ vn_emb,
                                                    float* __restrict__ vw,      // [257][64]
                                                    float* __restrict__ colsum){ // zeroed
    int wv = threadIdx.x >> 6, lane = threadIdx.x & 63;
    int b = blockIdx.x*4 + wv;
    float rold = root_old ? root_old[lane] : vn_emb[lane];
    float v = 0.f;
    #pragma unroll
    for (int s = 0; s < NSLICE; ++s)
        v += vseg[(size_t)(b*NSLICE + s)*64 + lane];
    v += (vd_old ? vd_old[b*64 + lane] : vn_emb[lane]) + rold;
    vw[b*64 + lane] = v;
    atomicAdd(&colsum[lane], v);
}

// root assembly (row 256 from colsum) + L x (Lin-ReLU-Lin-ReLU), 257 rows in place
__global__ __launch_bounds__(256) void k_vn_mlp(const float* __restrict__ colsum,
                                                const float* __restrict__ root_old,
                                                const float* __restrict__ vn_emb,
                                                const float* __restrict__ mlp_w1,
                                                const float* __restrict__ mlp_b1,
                                                const float* __restrict__ mlp_w2,
                                                const float* __restrict__ mlp_b2,
                                                int L, float* __restrict__ vw){
    __shared__ float Wl[64*64];
    int wv = blockIdx.x*4 + (threadIdx.x >> 6);
    int lane = threadIdx.x & 63;
    bool valid = (wv < 257);
    float iv = 0.f;
    if (valid){
        if (wv == 256){
            float rold = root_old ? root_old[lane] : vn_emb[lane];
            iv = colsum[lane] + rold;            // vn_root = colsum + vn_root_old
        } else {
            iv = vw[wv*64 + lane];
        }
    }
    for (int m = 0; m < L; ++m){
        #pragma unroll
        for (int half = 0; half < 2; ++half){
            const float* W    = (half ? mlp_w2 : mlp_w1) + (size_t)m*4096;
            const float* bias = (half ? mlp_b2 : mlp_b1) + (size_t)m*64;
            __syncthreads();
            for (int i = threadIdx.x; i < 4096; i += 256) Wl[i] = W[i];
            __syncthreads();
            float acc = bias[lane];
            #pragma unroll
            for (int k = 0; k < 64; ++k)
                acc += __shfl(iv, k, 64) * Wl[k*64 + lane];
            iv = fmaxf(acc, 0.f);
        }
    }
    if (valid) vw[wv*64 + lane] = iv;
}

extern "C" void kernel_launch(void* const* d_in, const int* in_sizes, int n_in,
                              void* d_out, int out_size, void* d_ws, size_t ws_size,
                              hipStream_t stream) {
    const int N = in_sizes[0] / 3;
    const int E = in_sizes[1] / 2;
    const int L = in_sizes[9] / (64*64);
    const int NB = (N + (1<<BSHIFT) - 1) >> BSHIFT;

    const float* x        = (const float*)d_in[0];
    const int*   edge     = (const int*)d_in[1];
    const int*   srcp     = edge;
    const int*   dstp     = edge + E;
    const int*   hb       = (const int*)d_in[2];
    const float* w_in     = (const float*)d_in[5];
    const float* a_src_in = (const float*)d_in[6];
    const float* a_dst_in = (const float*)d_in[7];
    const float* b_in     = (const float*)d_in[8];
    const float* w_l      = (const float*)d_in[9];
    const float* a_src_l  = (const float*)d_in[10];
    const float* a_dst_l  = (const float*)d_in[11];
    const float* b_l      = (const float*)d_in[12];
    const float* mlp_w1   = (const float*)d_in[13];
    const float* mlp_b1   = (const float*)d_in[14];
    const float* mlp_w2   = (const float*)d_in[15];
    const float* mlp_b2   = (const float*)d_in[16];
    const float* vn_emb   = (const float*)d_in[17];
    float*       out      = (float*)d_out;

    // ---- workspace carve (256B-aligned) ----
    char* ws = (char*)d_ws;
    size_t off = 0;
    auto carve = [&](size_t bytes) -> char* {
        char* p = ws + off;
        off = (off + bytes + 255) & ~(size_t)255;
        return p;
    };
    unsigned short* h = (unsigned short*)carve((size_t)N*64*2);  // aliased as pairs in CSR build
    float* outA   = (float*)carve((size_t)N*64*4);
    float* ssrc   = (float*)carve((size_t)N*4);
    float* sdst   = (float*)carve((size_t)N*4);
    int*   rowptr = (int*)carve((size_t)(N+1)*4);
    char*  zstart = ws + off;
    int*   bucketCount = (int*)carve(256*4);
    int*   hbBins = (int*)carve(256*4);
    float* colsum = (float*)carve(64*4);
    size_t zbytes = (size_t)((ws + off) - zstart);
    int*   bucketOff = (int*)carve(257*4);
    int*   bucketCur = (int*)carve(256*4);
    int*   binptr = (int*)carve(257*4);
    int*   bincur = (int*)carve(256*4);
    int*   colarr = (int*)carve((size_t)E*4);
    int*   nodes  = (int*)carve((size_t)N*4);
    float* vseg   = (float*)carve((size_t)256*NSLICE*64*4);
    float* vw     = (float*)carve((size_t)257*64*4);
    if (off > ws_size) return;
    int2* pairs = (int2*)h;   // E*8 <= N*128 bytes; pairs dead before h's first write

    // ---- CSR + node-bin build ----
    hipMemsetAsync(zstart, 0, zbytes, stream);
    const int nchunkE = (E + CHUNK - 1) / CHUNK;
    const int nchunkN = (N + CHUNK - 1) / CHUNK;
    k_count       <<<nchunkE, 256, 0, stream>>>(dstp, E, NB, bucketCount, hb, N, hbBins);
    k_scan_all    <<<1, 256, 0, stream>>>(bucketCount, NB, E, N, bucketOff, bucketCur, rowptr,
                                          hbBins, binptr, bincur);
    k_bucket_place<<<nchunkE, 256, 0, stream>>>(srcp, dstp, E, NB, bucketCur, pairs);
    k_bucket_csr  <<<NB, 256, 0, stream>>>(pairs, bucketOff, N, rowptr, colarr);
    k_hb_place    <<<nchunkN, 256, 0, stream>>>(hb, N, bincur, nodes);

    const int nwb = (N + 3) / 4;     // wave-per-node kernels
    const int nab = (N + 15) / 16;   // aggregate: 4 dst/wave, 16 dst/block
    const int nmb = (N + 63) / 64;   // mfma transform blocks

    // ---- GAT layer 0 (IN -> H) ----
    k_transform_in<<<nwb, 256, 0, stream>>>(x, w_in, a_src_in, a_dst_in, h, ssrc, sdst, N);
    k_aggregate<<<nab, 256, 0, stream>>>(h, ssrc, sdst, rowptr, colarr, b_in, outA, N);

    // ---- hidden layers ----
    for (int l = 0; l < L; ++l){
        const float* vnp = (l == 0) ? nullptr : vw;
        k_transform_h_mfma<<<nmb, 256, 0, stream>>>(outA, vnp, vn_emb, hb,
                                                    w_l + (size_t)l*4096,
                                                    a_src_l + (size_t)l*64,
                                                    a_dst_l + (size_t)l*64,
                                                    h, ssrc, sdst, N);
        const bool last = (l == L-1);
        float* dst_buf = last ? out : outA;
        k_aggregate<<<nab, 256, 0, stream>>>(h, ssrc, sdst, rowptr, colarr,
                                             b_l + (size_t)l*64, dst_buf, N);
        if (!last){
            const float* vdo = (l == 0) ? nullptr : vw;
            const float* ro  = (l == 0) ? nullptr : (vw + 256*64);
            k_vn_segsum2<<<256*NSLICE, 256, 0, stream>>>(outA, nodes, binptr, vseg);
            k_vn_combine<<<64, 256, 0, stream>>>(vseg, vdo, ro, vn_emb, vw, colsum);
            k_vn_mlp<<<(257+3)/4, 256, 0, stream>>>(colsum, ro, vn_emb,
                                                    mlp_w1, mlp_b1, mlp_w2, mlp_b2, L, vw);
        }
    }
}